// Round 5
// baseline (3310.590 us; speedup 1.0000x reference)
//
#include <hip/hip_runtime.h>
#include <cstdint>
#include <cstddef>

// Problem constants
#define NUM_C 4096
#define BB 32
#define TT 512
#define DD 128
#define MM 50

using ull = unsigned long long;

__device__ __forceinline__ float sigmoidf_(float x){ return 1.0f/(1.0f + expf(-x)); }

// Fast transcendentals on the serial critical path: v_exp_f32 / v_rcp_f32
__device__ __forceinline__ float fexp2_(float x){ return __builtin_amdgcn_exp2f(x); }
__device__ __forceinline__ float frcp_(float x){ return __builtin_amdgcn_rcpf(x); }
__device__ __forceinline__ float fast_sig_(float x){
  return frcp_(1.0f + fexp2_(-1.44269504088896341f*x));
}
__device__ __forceinline__ float fast_tanh_(float x){
  float t = fexp2_(2.88539008177792681f*x);     // e^(2x)
  return 1.0f - 2.0f*frcp_(t + 1.0f);
}

// Quad reduction via DPP (VALU pipe, no LDS): sum over lanes {x, x^1, x^2, x^3}
__device__ __forceinline__ float quadSum_(float v){
  int t = __builtin_amdgcn_update_dpp(0, __float_as_int(v), 0xB1, 0xF, 0xF, true);
  v += __int_as_float(t);
  t = __builtin_amdgcn_update_dpp(0, __float_as_int(v), 0x4E, 0xF, 0xF, true);
  v += __int_as_float(t);
  return v;
}

// Relaxed barrier: LDS visibility only (no vmcnt/expcnt drain). Safe when no
// intra-kernel global-memory RAW across the barrier.
__device__ __forceinline__ void barL_(){
  asm volatile("s_waitcnt lgkmcnt(0)\n\ts_barrier" ::: "memory");
}

// ---------------------------------------------------------------------------
// Kernel A: parallel precompute (unchanged).
// ---------------------------------------------------------------------------
__global__ __launch_bounds__(256) void kPre(
    const int* __restrict__ q, const int* __restrict__ r,
    const float* __restrict__ k_emb, const float* __restrict__ Mk,
    const float* __restrict__ f_W, const float* __restrict__ f_b,
    const float* __restrict__ a_W, const float* __restrict__ a_b,
    float* __restrict__ wAll, ull* __restrict__ keyLo, ull* __restrict__ keyHi,
    float* __restrict__ fpre, float* __restrict__ ypre)
{
  const int b = blockIdx.y, t0 = blockIdx.x * 32, tid = threadIdx.x;
  __shared__ __align__(16) float sK[32*129];
  __shared__ int sQ[32];
  __shared__ int sR[32];
  __shared__ union UU {
    struct { float sMk[MM*129]; double sZ[32*MM]; } p2;
    float sW2[128*65];
  } u;

  if (tid < 32){ sQ[tid] = q[b*TT + t0 + tid]; sR[tid] = r[b*TT + t0 + tid]; }
  __syncthreads();
  for (int i = tid; i < 32*128; i += 256){
    int tl = i >> 7, j = i & 127;
    sK[tl*129 + j] = k_emb[(size_t)sQ[tl]*DD + j];
  }
  for (int i = tid; i < MM*128; i += 256){
    int m = i >> 7, j = i & 127;
    u.p2.sMk[m*129 + j] = Mk[i];
  }
  __syncthreads();

  for (int idx = tid; idx < 32*MM; idx += 256){
    int tl = idx / MM, m = idx - tl*MM;
    double z = 0.0;
    for (int j = 0; j < DD; j++)
      z += (double)sK[tl*129 + j] * (double)u.p2.sMk[m*129 + j];
    u.p2.sZ[tl*MM + m] = z;
  }
  __syncthreads();

  {
    int tl = tid >> 3, l8 = tid & 7;
    double zmax = -1e300;
    for (int m = l8; m < MM; m += 8) zmax = fmax(zmax, u.p2.sZ[tl*MM + m]);
    for (int s = 1; s < 8; s <<= 1) zmax = fmax(zmax, __shfl_xor(zmax, s));
    double se = 0.0;
    for (int m = l8; m < MM; m += 8){
      double e = exp(u.p2.sZ[tl*MM + m] - zmax);
      u.p2.sZ[tl*MM + m] = e;
      se += e;
    }
    for (int s = 1; s < 8; s <<= 1) se += __shfl_xor(se, s);
    double inv = 1.0 / se;
    ull klo = 0, khi = 0;
    for (int m = l8; m < MM; m += 8){
      double w = u.p2.sZ[tl*MM + m] * inv;
      wAll[((size_t)(b*TT + t0 + tl))*MM + m] = (float)w;
      double tw = fmin((w - 0.075)/(0.088 - 0.075), (1.0 - w)/(1.0 - 0.088));
      tw = fmax(tw, 0.0);
      ull iv = (tw >= 0.6) ? 2ull : ((tw >= 0.1) ? 1ull : 0ull);
      if (m < 32) klo |= iv << (2*m); else khi |= iv << (2*(m-32));
    }
    for (int s = 1; s < 8; s <<= 1){ klo |= __shfl_xor(klo, s); khi |= __shfl_xor(khi, s); }
    if (l8 == 0){ keyLo[b*TT + t0 + tl] = klo; keyHi[b*TT + t0 + tl] = khi; }
  }

  {
    const int dq = tid & 31, tq = tid >> 5;
    float acc[4][4];
    #pragma unroll
    for (int a = 0; a < 4; a++){ acc[a][0]=0.f; acc[a][1]=0.f; acc[a][2]=0.f; acc[a][3]=0.f; }
    for (int jh = 0; jh < 2; jh++){
      __syncthreads();
      for (int i = tid; i < 128*64; i += 256){
        int dd = i >> 6, jj = i & 63;
        u.sW2[dd*65 + jj] = f_W[dd*256 + 128 + jh*64 + jj];
      }
      __syncthreads();
      for (int jj = 0; jj < 64; jj++){
        float kv[4], wv[4];
        #pragma unroll
        for (int a = 0; a < 4; a++) kv[a] = sK[(tq*4 + a)*129 + jh*64 + jj];
        #pragma unroll
        for (int c = 0; c < 4; c++) wv[c] = u.sW2[(dq*4 + c)*65 + jj];
        #pragma unroll
        for (int a = 0; a < 4; a++){
          acc[a][0] += kv[a]*wv[0]; acc[a][1] += kv[a]*wv[1];
          acc[a][2] += kv[a]*wv[2]; acc[a][3] += kv[a]*wv[3];
        }
      }
    }
    #pragma unroll
    for (int a = 0; a < 4; a++){
      int tl = tq*4 + a;
      #pragma unroll
      for (int c = 0; c < 4; c++){
        int d = dq*4 + c;
        fpre[((size_t)(b*TT + t0 + tl))*DD + d] = acc[a][c] + f_b[d];
      }
    }
  }

  for (int i = tid; i < 32*DD; i += 256){
    int tl = i >> 7, d = i & 127;
    ypre[((size_t)(b*TT + t0 + tl))*DD + d] =
        a_W[(size_t)d*(NUM_C + DD) + sQ[tl]] * (float)sR[tl] + a_b[d];
  }
}

// ---------------------------------------------------------------------------
// Kernel A2: exact match search (unchanged).
// ---------------------------------------------------------------------------
__global__ __launch_bounds__(512) void kMatch(
    const ull* __restrict__ keyLo, const ull* __restrict__ keyHi, int* __restrict__ prevA)
{
  const int b = blockIdx.x, i = threadIdx.x;
  __shared__ ull slo[TT];
  __shared__ ull shi[TT];
  slo[i] = keyLo[b*TT + i];
  shi[i] = keyHi[b*TT + i];
  __syncthreads();
  const ull mylo = slo[i], myhi = shi[i];
  int found = -1;
  for (int j = i - 1; j >= 0; j--){
    if (slo[j] == mylo && shi[j] == myhi){ found = j; break; }
  }
  prevA[b*TT + i] = found;
}

// ---------------------------------------------------------------------------
// Kernel W: one-time weight products (unchanged).
// ---------------------------------------------------------------------------
__global__ __launch_bounds__(128) void kWW(
    const float* __restrict__ e_W, const float* __restrict__ add_W,
    const float* __restrict__ a_W,
    float* __restrict__ Ge, float* __restrict__ Ga)
{
  const int d = blockIdx.x;    // 0..127
  const int k = threadIdx.x;   // 0..127
  __shared__ float se[128];
  __shared__ float sa[128];
  se[k] = e_W[(size_t)d*DD + k];
  sa[k] = add_W[(size_t)d*DD + k];
  __syncthreads();
  float ge = 0.f, ga = 0.f;
  for (int j = 0; j < DD; j++){
    float af = a_W[(size_t)j*(NUM_C + DD) + NUM_C + k];
    ge += se[j]*af;
    ga += sa[j]*af;
  }
  Ge[(size_t)d*DD + k] = ge;
  Ga[(size_t)d*DD + k] = ga;
}

// ---------------------------------------------------------------------------
// Kernel EA: eapre GEMM, INTERLEAVED output (unchanged from R8):
//   eapre[row][2*d] = epre(d), eapre[row][2*d+1] = apre(d)
// ---------------------------------------------------------------------------
__global__ __launch_bounds__(256) void kEA(
    const float* __restrict__ ypre, const float* __restrict__ e_W,
    const float* __restrict__ add_W, const float* __restrict__ e_b,
    const float* __restrict__ add_b, float* __restrict__ eapre)
{
  const int jt = blockIdx.x;   // 0..3  (64 output cols each)
  const int rt = blockIdx.y;   // 0..511 (32 rows each)
  const int tid = threadIdx.x;
  __shared__ float sW[64*129];
  __shared__ float sF[32*129];
  for (int i = tid; i < 64*128; i += 256){
    int jj = i >> 7, k = i & 127;
    int j = jt*64 + jj;
    sW[jj*129 + k] = (j < 128) ? e_W[(size_t)j*DD + k] : add_W[(size_t)(j-128)*DD + k];
  }
  for (int i = tid; i < 32*128; i += 256){
    int rr = i >> 7, k = i & 127;
    sF[rr*129 + k] = ypre[(size_t)(rt*32 + rr)*DD + k];
  }
  __syncthreads();
  const int jq = tid & 31, rq = tid >> 5;
  float acc[4][2];
  #pragma unroll
  for (int a = 0; a < 4; a++){ acc[a][0] = 0.f; acc[a][1] = 0.f; }
  for (int k = 0; k < 128; k++){
    float fv[4], wv[2];
    #pragma unroll
    for (int a = 0; a < 4; a++) fv[a] = sF[(rq*4 + a)*129 + k];
    wv[0] = sW[(jq*2 + 0)*129 + k];
    wv[1] = sW[(jq*2 + 1)*129 + k];
    #pragma unroll
    for (int a = 0; a < 4; a++){ acc[a][0] += fv[a]*wv[0]; acc[a][1] += fv[a]*wv[1]; }
  }
  #pragma unroll
  for (int a = 0; a < 4; a++){
    int rowi = rt*32 + rq*4 + a;
    #pragma unroll
    for (int c = 0; c < 2; c++){
      int j = jt*64 + jq*2 + c;
      float bj = (j < 128) ? e_b[j] : add_b[j - 128];
      int jj2 = (j < 128) ? (2*j) : (2*(j - 128) + 1);
      eapre[(size_t)rowi*256 + jj2] = acc[a][c] + bj;
    }
  }
}

// ---------------------------------------------------------------------------
// Kernel SS: ss[b][t] = sum_m w[b][t][m]*w[b][t+1][m]  (unchanged).
// ---------------------------------------------------------------------------
__global__ __launch_bounds__(512) void kSS(
    const float* __restrict__ wAll, float* __restrict__ ssAll)
{
  const int b = blockIdx.x, t = threadIdx.x;
  float s = 0.f;
  if (t < TT - 1){
    const float* w0 = &wAll[((size_t)b*TT + t)*MM];
    #pragma unroll
    for (int m = 0; m < MM; m++) s += w0[m]*w0[m + MM];
  }
  ssAll[(size_t)b*TT + t] = s;
}

// ---------------------------------------------------------------------------
// Kernel B (R9): memory recurrence, wave-split batch pairing.
//  - 512 threads: waves 0-3 = batch bp, waves 4-7 = batch bp+16.
//    Each SIMD hosts one wave from EACH batch: two independent serial chains
//    hide each other's LDS/DPP/transcendental latency (R8's loss was 1
//    wave/SIMD exposing all stalls; R7's loss was per-thread state
//    duplication -> spill. This gets TLP with NO extra per-thread state).
//  - per-batch thread layout = R8: thread (dd = lt>>2) owns dd and dd+64,
//    sharing the broadcast-vector LDS reads between both outputs.
//  - chunk staging load-at-boundary (no cross-chunk prefetch registers):
//    frees ~15 persistent VGPRs to fit the 256/wave budget at 2 waves/SIMD.
//  - relaxed lgkm-only barriers; no global RAW inside the kernel.
//  Per-output arithmetic order identical to R6/R8 -> bit-identical results.
// ---------------------------------------------------------------------------
__global__ __launch_bounds__(512, 2) __attribute__((amdgpu_waves_per_eu(2, 2)))
void kMem(
    const float* __restrict__ wAll, const float* __restrict__ fpre,
    const float* __restrict__ eapre,
    const float* __restrict__ f_W, const float* __restrict__ Ge,
    const float* __restrict__ Ga,
    const float* __restrict__ Mv0, const float* __restrict__ ssAll,
    float* __restrict__ fAll)
{
  const int bp = blockIdx.x, tid = threadIdx.x;
  const int g  = tid >> 8;               // batch half: 0 -> bp, 1 -> bp+16
  const int lt = tid & 255;              // local tid within batch half
  const int b  = bp + 16*g;
  const int dd  = lt >> 2;               // 0..63 ; owns dd and dd+64
  const int ddB = dd + 64;
  const int kc  = lt & 3;                // quad lane: K-slice / m-slice selector
  const int m0  = kc*13;                 // m-chunk base (13,13,13,11)
  const int wslotA = (dd  >> 5)*36 + (dd  & 31);
  const int wslotB = (ddB >> 5)*36 + (ddB & 31);

  // register-resident state & weights (both output rows)
  float mv0[13], mv1[13];
  #pragma unroll
  for (int i = 0; i < 13; i++){
    int m = m0 + i;
    mv0[i] = (m < MM) ? Mv0[(size_t)m*DD + dd ] : 0.f;
    mv1[i] = (m < MM) ? Mv0[(size_t)m*DD + ddB] : 0.f;
  }
  float wf0[32], wf1[32], ge0[32], ge1[32], ga0[32], ga1[32];
  {
    const float4* p;
    p = reinterpret_cast<const float4*>(&f_W[dd*256 + kc*32]);
    #pragma unroll
    for (int i = 0; i < 8; i++){ float4 v = p[i]; wf0[4*i]=v.x; wf0[4*i+1]=v.y; wf0[4*i+2]=v.z; wf0[4*i+3]=v.w; }
    p = reinterpret_cast<const float4*>(&f_W[ddB*256 + kc*32]);
    #pragma unroll
    for (int i = 0; i < 8; i++){ float4 v = p[i]; wf1[4*i]=v.x; wf1[4*i+1]=v.y; wf1[4*i+2]=v.z; wf1[4*i+3]=v.w; }
    p = reinterpret_cast<const float4*>(&Ge[(size_t)dd*DD + kc*32]);
    #pragma unroll
    for (int i = 0; i < 8; i++){ float4 v = p[i]; ge0[4*i]=v.x; ge0[4*i+1]=v.y; ge0[4*i+2]=v.z; ge0[4*i+3]=v.w; }
    p = reinterpret_cast<const float4*>(&Ge[(size_t)ddB*DD + kc*32]);
    #pragma unroll
    for (int i = 0; i < 8; i++){ float4 v = p[i]; ge1[4*i]=v.x; ge1[4*i+1]=v.y; ge1[4*i+2]=v.z; ge1[4*i+3]=v.w; }
    p = reinterpret_cast<const float4*>(&Ga[(size_t)dd*DD + kc*32]);
    #pragma unroll
    for (int i = 0; i < 8; i++){ float4 v = p[i]; ga0[4*i]=v.x; ga0[4*i+1]=v.y; ga0[4*i+2]=v.z; ga0[4*i+3]=v.w; }
    p = reinterpret_cast<const float4*>(&Ga[(size_t)ddB*DD + kc*32]);
    #pragma unroll
    for (int i = 0; i < 8; i++){ float4 v = p[i]; ga1[4*i]=v.x; ga1[4*i+1]=v.y; ga1[4*i+2]=v.z; ga1[4*i+3]=v.w; }
  }

  __shared__ __align__(16) float bufR[2][144];
  __shared__ __align__(16) float bufF[2][144];
  __shared__ __align__(16) float sW9[2][9*64];  // 4x16 padded slices; pads 0
  __shared__ float sS8[2][8];
  __shared__ __align__(16) float sF8[2][8*128];
  __shared__ __align__(16) float sEA8[2][8*256]; // interleaved (e,a) pairs
  __shared__ __align__(16) float fO8[2][8*128];

  const size_t base = (size_t)b*TT;
  // w staging: 450 values per batch, 2 slots/thread; slice-padded position
  const int rrA = lt/50, mmA = lt - rrA*50;
  const int kcsA = mmA/13;
  const int slotA_ = rrA*64 + kcsA*16 + (mmA - kcsA*13);
  const int idx1 = lt + 256;
  const int rrB_ = idx1/50, mmB_ = idx1 - rrB_*50;
  const int kcsB = mmB_/13;
  const int slotB_ = rrB_*64 + kcsB*16 + (mmB_ - kcsB*13);
  const bool hasB = (idx1 < 450);

  // zero own batch's sW9 once (pads stay 0; data slots overwritten each chunk)
  for (int i = lt; i < 9*64; i += 256) sW9[g][i] = 0.f;
  barL_();   // zero-init visible before first publish

  float wreg[13];   // w_t for the current step (rotated from wn)

  for (int ch = 0; ch < TT/8; ch++){
    const int t0 = ch*8;
    if (ch){
      float4 v = reinterpret_cast<const float4*>(fO8[g])[lt];
      reinterpret_cast<float4*>(&fAll[(base + t0 - 8)*DD])[lt] = v;
    }
    // boundary staging: global -> reg -> LDS (compiler inserts vmcnt waits).
    // ~one L3 round trip per 8 steps; hidden partly by the paired batch.
    {
      float4 vF  = reinterpret_cast<const float4*>(&fpre[(base + t0)*DD])[lt];
      float4 vE0 = reinterpret_cast<const float4*>(&eapre[(base + t0)*256])[lt];
      float4 vE1 = reinterpret_cast<const float4*>(&eapre[(base + t0)*256])[lt + 256];
      float w0 = wAll[(base + t0 + rrA)*MM + mmA];           // t0+rrA <= 504+5 < 512
      float w1 = (hasB && (t0 + rrB_ < TT)) ? wAll[(base + t0 + rrB_)*MM + mmB_] : 0.f;
      float sv = (lt < 8) ? ssAll[base + t0 + lt] : 0.f;
      reinterpret_cast<float4*>(sF8[g])[lt] = vF;
      reinterpret_cast<float4*>(sEA8[g])[lt] = vE0;
      reinterpret_cast<float4*>(sEA8[g])[lt + 256] = vE1;
      sW9[g][slotA_] = w0;
      if (hasB) sW9[g][slotB_] = w1;
      if (lt < 8) sS8[g][lt] = sv;
    }
    barL_();   // R: chunk published

    if (ch == 0){
      #pragma unroll
      for (int i = 0; i < 13; i++) wreg[i] = sW9[g][kc*16 + i];
      float rA = 0.f, rB = 0.f;
      #pragma unroll
      for (int i = 0; i < 13; i++){ rA += wreg[i]*mv0[i]; rB += wreg[i]*mv1[i]; }
      rA = quadSum_(rA); rB = quadSum_(rB);
      if (kc == 0){ bufR[g][wslotA] = rA; bufR[g][wslotB] = rB; }
      barL_();
    }

    #pragma unroll
    for (int tc = 0; tc < 8; tc++){
      // w_{t+1}: 4x b128 from the padded slice (entries 13..15 are zero)
      float wn[16];
      {
        const float4* w4 = reinterpret_cast<const float4*>(&sW9[g][(tc+1)*64 + kc*16]);
        float4 v0 = w4[0], v1 = w4[1], v2 = w4[2], v3 = w4[3];
        wn[0]=v0.x; wn[1]=v0.y; wn[2]=v0.z; wn[3]=v0.w;
        wn[4]=v1.x; wn[5]=v1.y; wn[6]=v1.z; wn[7]=v1.w;
        wn[8]=v2.x; wn[9]=v2.y; wn[10]=v2.z; wn[11]=v2.w;
        wn[12]=v3.x; wn[13]=v3.y; wn[14]=v3.z; wn[15]=v3.w;
      }

      // ---- stage F: f = tanh(read @ f_Wr.T + fpre) for dd and dd+64 ----
      float r0a=0.f, r1a=0.f, r0b=0.f, r1b=0.f;
      {
        const float4* x4 = reinterpret_cast<const float4*>(&bufR[g][kc*36]);
        float aA0=0.f,aA1=0.f,aA2=0.f,aA3=0.f;
        float aB0=0.f,aB1=0.f,aB2=0.f,aB3=0.f;
        #pragma unroll
        for (int i = 0; i < 8; i++){
          float4 xv = x4[i];
          aA0 += xv.x*wf0[4*i]; aA1 += xv.y*wf0[4*i+1]; aA2 += xv.z*wf0[4*i+2]; aA3 += xv.w*wf0[4*i+3];
          aB0 += xv.x*wf1[4*i]; aB1 += xv.y*wf1[4*i+1]; aB2 += xv.z*wf1[4*i+2]; aB3 += xv.w*wf1[4*i+3];
        }
        // off-critical-path: next-step read components from pre-update mv
        #pragma unroll
        for (int i = 0; i < 13; i++){
          float ww = wn[i]*wreg[i];
          r0a += wn[i]*mv0[i];
          r1a += ww*mv0[i];
          r0b += wn[i]*mv1[i];
          r1b += ww*mv1[i];
        }
        float sA = quadSum_((aA0+aA1)+(aA2+aA3));
        float sB = quadSum_((aB0+aB1)+(aB2+aB3));
        float fA = fast_tanh_(sA + sF8[g][tc*128 + dd ]);
        float fB = fast_tanh_(sB + sF8[g][tc*128 + ddB]);
        if (kc == 0){
          bufF[g][wslotA] = fA; fO8[g][tc*128 + dd ] = fA;
          bufF[g][wslotB] = fB; fO8[g][tc*128 + ddB] = fB;
        }
        r0a = quadSum_(r0a); r1a = quadSum_(r1a);
        r0b = quadSum_(r0b); r1b = quadSum_(r1b);
      }
      barL_();   // B

      // ---- stage EA: e,a from f; read_{t+1}; mv update (both rows) ----
      {
        const float4* x4 = reinterpret_cast<const float4*>(&bufF[g][kc*36]);
        float eA0=0.f,eA1=0.f,gA0=0.f,gA1=0.f;
        float eB0=0.f,eB1=0.f,gB0=0.f,gB1=0.f;
        #pragma unroll
        for (int i = 0; i < 8; i++){
          float4 xv = x4[i];
          eA0 += xv.x*ge0[4*i];   eA1 += xv.y*ge0[4*i+1];
          eA0 += xv.z*ge0[4*i+2]; eA1 += xv.w*ge0[4*i+3];
          gA0 += xv.x*ga0[4*i];   gA1 += xv.y*ga0[4*i+1];
          gA0 += xv.z*ga0[4*i+2]; gA1 += xv.w*ga0[4*i+3];
          eB0 += xv.x*ge1[4*i];   eB1 += xv.y*ge1[4*i+1];
          eB0 += xv.z*ge1[4*i+2]; eB1 += xv.w*ge1[4*i+3];
          gB0 += xv.x*ga1[4*i];   gB1 += xv.y*ga1[4*i+1];
          gB0 += xv.z*ga1[4*i+2]; gB1 += xv.w*ga1[4*i+3];
        }
        float epA = quadSum_(eA0 + eA1);
        float apA = quadSum_(gA0 + gA1);
        float epB = quadSum_(eB0 + eB1);
        float apB = quadSum_(gB0 + gB1);
        float2 eaA = *reinterpret_cast<const float2*>(&sEA8[g][tc*256 + 2*dd ]);
        float2 eaB = *reinterpret_cast<const float2*>(&sEA8[g][tc*256 + 2*ddB]);
        float e_dA = fast_sig_(epA + eaA.x);
        float a_dA = fast_tanh_(apA + eaA.y);
        float e_dB = fast_sig_(epB + eaB.x);
        float a_dB = fast_tanh_(apB + eaB.y);
        float ssv = sS8[g][tc];
        if (kc == 0){
          bufR[g][wslotA] = r0a - e_dA*r1a + a_dA*ssv;   // read_{t+1} (dd)
          bufR[g][wslotB] = r0b - e_dB*r1b + a_dB*ssv;   // read_{t+1} (dd+64)
        }
        #pragma unroll
        for (int i = 0; i < 13; i++){
          float wv = wreg[i];
          mv0[i] = mv0[i]*(1.f - wv*e_dA) + wv*a_dA;
          mv1[i] = mv1[i]*(1.f - wv*e_dB) + wv*a_dB;
        }
      }
      #pragma unroll
      for (int i = 0; i < 13; i++) wreg[i] = wn[i];
      barL_();   // C
    }
  }

  {
    float4 v = reinterpret_cast<const float4*>(fO8[g])[lt];
    reinterpret_cast<float4*>(&fAll[(base + TT - 8)*DD])[lt] = v;
  }
}

// ---------------------------------------------------------------------------
// Kernel D: gpre GEMM (unchanged).
// ---------------------------------------------------------------------------
__global__ __launch_bounds__(256) void kGate(
    const float* __restrict__ fAll, const float* __restrict__ Wih,
    const float* __restrict__ bih, const float* __restrict__ bhh,
    float* __restrict__ gpre)
{
  const int jt = blockIdx.x;
  const int rt = blockIdx.y;
  const int tid = threadIdx.x;
  __shared__ float sW[64*129];
  __shared__ float sF[32*129];
  for (int i = tid; i < 64*128; i += 256){
    int jj = i >> 7, k = i & 127;
    sW[jj*129 + k] = Wih[(size_t)(jt*64 + jj)*128 + k];
  }
  for (int i = tid; i < 32*128; i += 256){
    int rr = i >> 7, k = i & 127;
    sF[rr*129 + k] = fAll[(size_t)(rt*32 + rr)*128 + k];
  }
  __syncthreads();
  const int jq = tid & 31, rq = tid >> 5;
  float acc[4][2];
  #pragma unroll
  for (int a = 0; a < 4; a++){ acc[a][0] = 0.f; acc[a][1] = 0.f; }
  for (int k = 0; k < 128; k++){
    float fv[4], wv[2];
    #pragma unroll
    for (int a = 0; a < 4; a++) fv[a] = sF[(rq*4 + a)*129 + k];
    wv[0] = sW[(jq*2 + 0)*129 + k];
    wv[1] = sW[(jq*2 + 1)*129 + k];
    #pragma unroll
    for (int a = 0; a < 4; a++){ acc[a][0] += fv[a]*wv[0]; acc[a][1] += fv[a]*wv[1]; }
  }
  #pragma unroll
  for (int a = 0; a < 4; a++){
    int rowi = rt*32 + rq*4 + a;
    #pragma unroll
    for (int c = 0; c < 2; c++){
      int j = jt*64 + jq*2 + c;
      gpre[(size_t)rowi*512 + j] = acc[a][c] + bih[j] + bhh[j];
    }
  }
}

// ---------------------------------------------------------------------------
// Kernel C (R8, unchanged): LSTM with LDS ring + relaxed per-step barriers.
// ---------------------------------------------------------------------------
__global__ __launch_bounds__(512, 2) __attribute__((amdgpu_waves_per_eu(2, 2)))
void kLstm(
    const float* __restrict__ gpre, const int* __restrict__ prevA,
    const float* __restrict__ Whh,
    float* __restrict__ Hh, float* __restrict__ Ch)
{
  const int b = blockIdx.x, tid = threadIdx.x;
  const int jo = tid >> 2, kc = tid & 3;
  const int wslot = (jo >> 5)*36 + (jo & 31);

  float whh[4][32];
  #pragma unroll
  for (int g = 0; g < 4; g++){
    const float4* W4 = reinterpret_cast<const float4*>(&Whh[(size_t)(g*128 + jo)*128 + kc*32]);
    #pragma unroll
    for (int i = 0; i < 8; i++){
      float4 v = W4[i];
      whh[g][4*i] = v.x; whh[g][4*i+1] = v.y; whh[g][4*i+2] = v.z; whh[g][4*i+3] = v.w;
    }
  }

  __shared__ __align__(16) float xh[2][144];   // padded h_in broadcast (double buffer)
  __shared__ __align__(16) float gbuf[8*512];  // 16 KB gpre chunk
  __shared__ int spv[TT];
  __shared__ float hRing[8*128];               // last-8-steps h (in-chunk skips)
  __shared__ float cRing[8*128];

  const size_t base = (size_t)b*TT;
  float4 gr0, gr1;
  {
    const float4* g0 = reinterpret_cast<const float4*>(&gpre[base*512]);
    gr0 = g0[tid*2]; gr1 = g0[tid*2+1];
    spv[tid] = prevA[base + tid];
    if (tid < DD) xh[0][(tid >> 5)*36 + (tid & 31)] = 0.f;
  }

  float cin_cur = 0.f;

  for (int ch = 0; ch < TT/8; ch++){
    const int t0 = ch*8;
    if (ch) __syncthreads();           // FULL: drains prev chunk's Hh/Ch stores
    {
      float4* gb4 = reinterpret_cast<float4*>(gbuf);
      gb4[tid*2] = gr0; gb4[tid*2+1] = gr1;
      if (t0 + 8 < TT){
        const float4* gp4 = reinterpret_cast<const float4*>(&gpre[(base + t0 + 8)*512]);
        gr0 = gp4[tid*2]; gr1 = gp4[tid*2+1];
      }
    }
    barL_();                           // chunk published (+ xh ready for tc=0)

    #pragma unroll
    for (int tc = 0; tc < 8; tc++){
      const int t = t0 + tc, p = t & 1;
      if (tc) barL_();                 // xh[p] + ring ready

      int pv2 = -1; float preH = 0.f, preC = 0.f;
      if (t + 1 < TT){
        pv2 = spv[t + 1];
        if (pv2 >= 0 && pv2 < t){
          if (pv2 >= t0){              // in-chunk: LDS ring (barrier-ordered)
            preH = hRing[(pv2 & 7)*128 + jo];
            preC = cRing[(pv2 & 7)*128 + jo];
          } else {                     // older chunk: global, drained at boundary
            preH = Hh[(base + pv2)*DD + jo];
            preC = Ch[(base + pv2)*DD + jo];
          }
        }
      }

      float gp0 = gbuf[tc*512 + jo];
      float gp1 = gbuf[tc*512 + 128 + jo];
      float gp2 = gbuf[tc*512 + 256 + jo];
      float gp3 = gbuf[tc*512 + 384 + jo];

      float a0=0.f,a1=0.f,a2=0.f,a3=0.f;
      {
        const float4* x4 = reinterpret_cast<const float4*>(&xh[p][kc*36]);
        #pragma unroll
        for (int i = 0; i < 8; i++){
          float4 xv = x4[i];
          a0 += xv.x*whh[0][4*i]; a0 += xv.y*whh[0][4*i+1]; a0 += xv.z*whh[0][4*i+2]; a0 += xv.w*whh[0][4*i+3];
          a1 += xv.x*whh[1][4*i]; a1 += xv.y*whh[1][4*i+1]; a1 += xv.z*whh[1][4*i+2]; a1 += xv.w*whh[1][4*i+3];
          a2 += xv.x*whh[2][4*i]; a2 += xv.y*whh[2][4*i+1]; a2 += xv.z*whh[2][4*i+2]; a2 += xv.w*whh[2][4*i+3];
          a3 += xv.x*whh[3][4*i]; a3 += xv.y*whh[3][4*i+1]; a3 += xv.z*whh[3][4*i+2]; a3 += xv.w*whh[3][4*i+3];
        }
      }
      a0 = quadSum_(a0); a1 = quadSum_(a1); a2 = quadSum_(a2); a3 = quadSum_(a3);

      const float ig = gp0 + a0, fg = gp1 + a1, gg = gp2 + a2, og = gp3 + a3;
      const float cn = fast_sig_(fg)*cin_cur + fast_sig_(ig)*fast_tanh_(gg);
      const float hn = fast_sig_(og)*fast_tanh_(cn);

      if (kc == 0){
        Hh[(base + t)*DD + jo] = hn;
        Ch[(base + t)*DD + jo] = cn;
        hRing[(t & 7)*128 + jo] = hn;
        cRing[(t & 7)*128 + jo] = cn;
      }

      float hin_n, cin_n;
      if (pv2 < 0 || pv2 >= t){ hin_n = hn; cin_n = cn; }       // carry
      else                     { hin_n = preH; cin_n = preC; }   // skip
      if (kc == 0) xh[1 - p][wslot] = hin_n;
      cin_cur = cin_n;
    }
  }
}

// ---------------------------------------------------------------------------
// Kernel E: output head (unchanged).
// ---------------------------------------------------------------------------
__global__ __launch_bounds__(256) void kOut(
    const float* __restrict__ Hh, const float* __restrict__ p_W,
    const float* __restrict__ p_b, float* __restrict__ out)
{
  const int row = blockIdx.x*16 + (threadIdx.x >> 4);
  const int l = threadIdx.x & 15;
  const float4* h4 = reinterpret_cast<const float4*>(&Hh[(size_t)row*DD + l*8]);
  const float4* w4 = reinterpret_cast<const float4*>(&p_W[l*8]);
  float4 ha = h4[0], hb = h4[1], wa = w4[0], wb = w4[1];
  float s = ha.x*wa.x + ha.y*wa.y + ha.z*wa.z + ha.w*wa.w
          + hb.x*wb.x + hb.y*wb.y + hb.z*wb.z + hb.w*wb.w;
  s += __shfl_xor(s, 1); s += __shfl_xor(s, 2);
  s += __shfl_xor(s, 4); s += __shfl_xor(s, 8);
  if (l == 0) out[row] = sigmoidf_(s + p_b[0]);
}

// ---------------------------------------------------------------------------
// Launch.
// ---------------------------------------------------------------------------
extern "C" void kernel_launch(void* const* d_in, const int* in_sizes, int n_in,
                              void* d_out, int out_size, void* d_ws, size_t ws_size,
                              hipStream_t stream) {
  const int*   q     = (const int*)  d_in[0];
  const int*   r     = (const int*)  d_in[1];
  const float* k_emb = (const float*)d_in[2];
  const float* Mk    = (const float*)d_in[3];
  const float* Mv0   = (const float*)d_in[4];
  const float* f_W   = (const float*)d_in[5];
  const float* f_b   = (const float*)d_in[6];
  const float* a_W   = (const float*)d_in[7];
  const float* a_b   = (const float*)d_in[8];
  const float* e_W   = (const float*)d_in[9];
  const float* e_b   = (const float*)d_in[10];
  const float* add_W = (const float*)d_in[11];
  const float* add_b = (const float*)d_in[12];
  const float* Wih   = (const float*)d_in[13];
  const float* Whh   = (const float*)d_in[14];
  const float* bih   = (const float*)d_in[15];
  const float* bhh   = (const float*)d_in[16];
  const float* p_W   = (const float*)d_in[17];
  const float* p_b   = (const float*)d_in[18];
  float* out = (float*)d_out;

  char* ws = (char*)d_ws;
  size_t off = 0;
  auto alloc = [&](size_t bytes) -> char* {
    char* p = ws + off;
    off += (bytes + 255) & ~(size_t)255;
    return p;
  };
  float* wAll  = (float*)alloc((size_t)BB*TT*MM*4);
  float* fpre  = (float*)alloc((size_t)BB*TT*DD*4);
  float* ypre  = (float*)alloc((size_t)BB*TT*DD*4);
  float* fAll  = (float*)alloc((size_t)BB*TT*DD*4);
  float* gpre  = (float*)alloc((size_t)BB*TT*512*4);
  float* Hh    = (float*)alloc((size_t)BB*TT*DD*4);
  float* Ch    = (float*)alloc((size_t)BB*TT*DD*4);
  ull*   keyLo = (ull*)  alloc((size_t)BB*TT*8);
  ull*   keyHi = (ull*)  alloc((size_t)BB*TT*8);
  int*   prevA = (int*)  alloc((size_t)BB*TT*4);
  float* Ge    = (float*)alloc((size_t)DD*DD*4);
  float* Ga    = (float*)alloc((size_t)DD*DD*4);
  float* ssAll = (float*)alloc((size_t)BB*TT*4);
  // eapre aliases gpre: lifetimes are disjoint
  // (eapre: [kEA, kMem]; gpre: [kGate, kLstm]).
  float* eapre = gpre;
  (void)ws_size; (void)in_sizes; (void)n_in; (void)out_size;

  kPre  <<<dim3(16, 32), 256, 0, stream>>>(q, r, k_emb, Mk, f_W, f_b, a_W, a_b,
                                           wAll, keyLo, keyHi, fpre, ypre);
  kWW   <<<128, 128, 0, stream>>>(e_W, add_W, a_W, Ge, Ga);
  kEA   <<<dim3(4, 512), 256, 0, stream>>>(ypre, e_W, add_W, e_b, add_b, eapre);
  kSS   <<<32, 512, 0, stream>>>(wAll, ssAll);
  kMatch<<<32, 512, 0, stream>>>(keyLo, keyHi, prevA);
  kMem  <<<16, 512, 0, stream>>>(wAll, fpre, eapre, f_W, Ge, Ga, Mv0, ssAll, fAll);
  kGate <<<dim3(8, 512), 256, 0, stream>>>(fAll, Wih, bih, bhh, gpre);
  kLstm <<<32, 512, 0, stream>>>(gpre, prevA, Whh, Hh, Ch);
  kOut  <<<(BB*TT)/16, 256, 0, stream>>>(Hh, p_W, p_b, out);
}

// Round 6
// 1226.063 us; speedup vs baseline: 2.7002x; 2.7002x over previous
//
#include <hip/hip_runtime.h>
#include <cstdint>
#include <cstddef>

// Problem constants
#define NUM_C 4096
#define BB 32
#define TT 512
#define DD 128
#define MM 50

using ull = unsigned long long;

__device__ __forceinline__ float sigmoidf_(float x){ return 1.0f/(1.0f + expf(-x)); }

// Fast transcendentals on the serial critical path: v_exp_f32 / v_rcp_f32
__device__ __forceinline__ float fexp2_(float x){ return __builtin_amdgcn_exp2f(x); }
__device__ __forceinline__ float frcp_(float x){ return __builtin_amdgcn_rcpf(x); }
__device__ __forceinline__ float fast_sig_(float x){
  return frcp_(1.0f + fexp2_(-1.44269504088896341f*x));
}
__device__ __forceinline__ float fast_tanh_(float x){
  float t = fexp2_(2.88539008177792681f*x);     // e^(2x)
  return 1.0f - 2.0f*frcp_(t + 1.0f);
}

// Quad reduction via DPP (VALU pipe, no LDS): sum over lanes {x, x^1, x^2, x^3}
__device__ __forceinline__ float quadSum_(float v){
  int t = __builtin_amdgcn_update_dpp(0, __float_as_int(v), 0xB1, 0xF, 0xF, true);
  v += __int_as_float(t);
  t = __builtin_amdgcn_update_dpp(0, __float_as_int(v), 0x4E, 0xF, 0xF, true);
  v += __int_as_float(t);
  return v;
}

// Relaxed barrier: LDS visibility only (no vmcnt/expcnt drain). Safe when no
// intra-kernel global-memory RAW across the barrier. Keeps global prefetch
// loads and stores in flight across steps.
__device__ __forceinline__ void barL_(){
  asm volatile("s_waitcnt lgkmcnt(0)\n\ts_barrier" ::: "memory");
}

// ---------------------------------------------------------------------------
// Kernel A: parallel precompute (unchanged).
// ---------------------------------------------------------------------------
__global__ __launch_bounds__(256) void kPre(
    const int* __restrict__ q, const int* __restrict__ r,
    const float* __restrict__ k_emb, const float* __restrict__ Mk,
    const float* __restrict__ f_W, const float* __restrict__ f_b,
    const float* __restrict__ a_W, const float* __restrict__ a_b,
    float* __restrict__ wAll, ull* __restrict__ keyLo, ull* __restrict__ keyHi,
    float* __restrict__ fpre, float* __restrict__ ypre)
{
  const int b = blockIdx.y, t0 = blockIdx.x * 32, tid = threadIdx.x;
  __shared__ __align__(16) float sK[32*129];
  __shared__ int sQ[32];
  __shared__ int sR[32];
  __shared__ union UU {
    struct { float sMk[MM*129]; double sZ[32*MM]; } p2;
    float sW2[128*65];
  } u;

  if (tid < 32){ sQ[tid] = q[b*TT + t0 + tid]; sR[tid] = r[b*TT + t0 + tid]; }
  __syncthreads();
  for (int i = tid; i < 32*128; i += 256){
    int tl = i >> 7, j = i & 127;
    sK[tl*129 + j] = k_emb[(size_t)sQ[tl]*DD + j];
  }
  for (int i = tid; i < MM*128; i += 256){
    int m = i >> 7, j = i & 127;
    u.p2.sMk[m*129 + j] = Mk[i];
  }
  __syncthreads();

  for (int idx = tid; idx < 32*MM; idx += 256){
    int tl = idx / MM, m = idx - tl*MM;
    double z = 0.0;
    for (int j = 0; j < DD; j++)
      z += (double)sK[tl*129 + j] * (double)u.p2.sMk[m*129 + j];
    u.p2.sZ[tl*MM + m] = z;
  }
  __syncthreads();

  {
    int tl = tid >> 3, l8 = tid & 7;
    double zmax = -1e300;
    for (int m = l8; m < MM; m += 8) zmax = fmax(zmax, u.p2.sZ[tl*MM + m]);
    for (int s = 1; s < 8; s <<= 1) zmax = fmax(zmax, __shfl_xor(zmax, s));
    double se = 0.0;
    for (int m = l8; m < MM; m += 8){
      double e = exp(u.p2.sZ[tl*MM + m] - zmax);
      u.p2.sZ[tl*MM + m] = e;
      se += e;
    }
    for (int s = 1; s < 8; s <<= 1) se += __shfl_xor(se, s);
    double inv = 1.0 / se;
    ull klo = 0, khi = 0;
    for (int m = l8; m < MM; m += 8){
      double w = u.p2.sZ[tl*MM + m] * inv;
      wAll[((size_t)(b*TT + t0 + tl))*MM + m] = (float)w;
      double tw = fmin((w - 0.075)/(0.088 - 0.075), (1.0 - w)/(1.0 - 0.088));
      tw = fmax(tw, 0.0);
      ull iv = (tw >= 0.6) ? 2ull : ((tw >= 0.1) ? 1ull : 0ull);
      if (m < 32) klo |= iv << (2*m); else khi |= iv << (2*(m-32));
    }
    for (int s = 1; s < 8; s <<= 1){ klo |= __shfl_xor(klo, s); khi |= __shfl_xor(khi, s); }
    if (l8 == 0){ keyLo[b*TT + t0 + tl] = klo; keyHi[b*TT + t0 + tl] = khi; }
  }

  {
    const int dq = tid & 31, tq = tid >> 5;
    float acc[4][4];
    #pragma unroll
    for (int a = 0; a < 4; a++){ acc[a][0]=0.f; acc[a][1]=0.f; acc[a][2]=0.f; acc[a][3]=0.f; }
    for (int jh = 0; jh < 2; jh++){
      __syncthreads();
      for (int i = tid; i < 128*64; i += 256){
        int dd = i >> 6, jj = i & 63;
        u.sW2[dd*65 + jj] = f_W[dd*256 + 128 + jh*64 + jj];
      }
      __syncthreads();
      for (int jj = 0; jj < 64; jj++){
        float kv[4], wv[4];
        #pragma unroll
        for (int a = 0; a < 4; a++) kv[a] = sK[(tq*4 + a)*129 + jh*64 + jj];
        #pragma unroll
        for (int c = 0; c < 4; c++) wv[c] = u.sW2[(dq*4 + c)*65 + jj];
        #pragma unroll
        for (int a = 0; a < 4; a++){
          acc[a][0] += kv[a]*wv[0]; acc[a][1] += kv[a]*wv[1];
          acc[a][2] += kv[a]*wv[2]; acc[a][3] += kv[a]*wv[3];
        }
      }
    }
    #pragma unroll
    for (int a = 0; a < 4; a++){
      int tl = tq*4 + a;
      #pragma unroll
      for (int c = 0; c < 4; c++){
        int d = dq*4 + c;
        fpre[((size_t)(b*TT + t0 + tl))*DD + d] = acc[a][c] + f_b[d];
      }
    }
  }

  for (int i = tid; i < 32*DD; i += 256){
    int tl = i >> 7, d = i & 127;
    ypre[((size_t)(b*TT + t0 + tl))*DD + d] =
        a_W[(size_t)d*(NUM_C + DD) + sQ[tl]] * (float)sR[tl] + a_b[d];
  }
}

// ---------------------------------------------------------------------------
// Kernel A2: exact match search (unchanged).
// ---------------------------------------------------------------------------
__global__ __launch_bounds__(512) void kMatch(
    const ull* __restrict__ keyLo, const ull* __restrict__ keyHi, int* __restrict__ prevA)
{
  const int b = blockIdx.x, i = threadIdx.x;
  __shared__ ull slo[TT];
  __shared__ ull shi[TT];
  slo[i] = keyLo[b*TT + i];
  shi[i] = keyHi[b*TT + i];
  __syncthreads();
  const ull mylo = slo[i], myhi = shi[i];
  int found = -1;
  for (int j = i - 1; j >= 0; j--){
    if (slo[j] == mylo && shi[j] == myhi){ found = j; break; }
  }
  prevA[b*TT + i] = found;
}

// ---------------------------------------------------------------------------
// Kernel W: one-time weight products (unchanged).
// ---------------------------------------------------------------------------
__global__ __launch_bounds__(128) void kWW(
    const float* __restrict__ e_W, const float* __restrict__ add_W,
    const float* __restrict__ a_W,
    float* __restrict__ Ge, float* __restrict__ Ga)
{
  const int d = blockIdx.x;    // 0..127
  const int k = threadIdx.x;   // 0..127
  __shared__ float se[128];
  __shared__ float sa[128];
  se[k] = e_W[(size_t)d*DD + k];
  sa[k] = add_W[(size_t)d*DD + k];
  __syncthreads();
  float ge = 0.f, ga = 0.f;
  for (int j = 0; j < DD; j++){
    float af = a_W[(size_t)j*(NUM_C + DD) + NUM_C + k];
    ge += se[j]*af;
    ga += sa[j]*af;
  }
  Ge[(size_t)d*DD + k] = ge;
  Ga[(size_t)d*DD + k] = ga;
}

// ---------------------------------------------------------------------------
// Kernel EA: eapre GEMM (R6 layout: [row][j], j<128 = epre, j>=128 = apre).
// ---------------------------------------------------------------------------
__global__ __launch_bounds__(256) void kEA(
    const float* __restrict__ ypre, const float* __restrict__ e_W,
    const float* __restrict__ add_W, const float* __restrict__ e_b,
    const float* __restrict__ add_b, float* __restrict__ eapre)
{
  const int jt = blockIdx.x;   // 0..3  (64 output cols each)
  const int rt = blockIdx.y;   // 0..511 (32 rows each)
  const int tid = threadIdx.x;
  __shared__ float sW[64*129];
  __shared__ float sF[32*129];
  for (int i = tid; i < 64*128; i += 256){
    int jj = i >> 7, k = i & 127;
    int j = jt*64 + jj;
    sW[jj*129 + k] = (j < 128) ? e_W[(size_t)j*DD + k] : add_W[(size_t)(j-128)*DD + k];
  }
  for (int i = tid; i < 32*128; i += 256){
    int rr = i >> 7, k = i & 127;
    sF[rr*129 + k] = ypre[(size_t)(rt*32 + rr)*DD + k];
  }
  __syncthreads();
  const int jq = tid & 31, rq = tid >> 5;
  float acc[4][2];
  #pragma unroll
  for (int a = 0; a < 4; a++){ acc[a][0] = 0.f; acc[a][1] = 0.f; }
  for (int k = 0; k < 128; k++){
    float fv[4], wv[2];
    #pragma unroll
    for (int a = 0; a < 4; a++) fv[a] = sF[(rq*4 + a)*129 + k];
    wv[0] = sW[(jq*2 + 0)*129 + k];
    wv[1] = sW[(jq*2 + 1)*129 + k];
    #pragma unroll
    for (int a = 0; a < 4; a++){ acc[a][0] += fv[a]*wv[0]; acc[a][1] += fv[a]*wv[1]; }
  }
  #pragma unroll
  for (int a = 0; a < 4; a++){
    int rowi = rt*32 + rq*4 + a;
    #pragma unroll
    for (int c = 0; c < 2; c++){
      int j = jt*64 + jq*2 + c;
      float bj = (j < 128) ? e_b[j] : add_b[j - 128];
      eapre[(size_t)rowi*256 + j] = acc[a][c] + bj;
    }
  }
}

// ---------------------------------------------------------------------------
// Kernel SS: ss[b][t] = sum_m w[b][t][m]*w[b][t+1][m]  (unchanged).
// ---------------------------------------------------------------------------
__global__ __launch_bounds__(512) void kSS(
    const float* __restrict__ wAll, float* __restrict__ ssAll)
{
  const int b = blockIdx.x, t = threadIdx.x;
  float s = 0.f;
  if (t < TT - 1){
    const float* w0 = &wAll[((size_t)b*TT + t)*MM];
    #pragma unroll
    for (int m = 0; m < MM; m++) s += w0[m]*w0[m + MM];
  }
  ssAll[(size_t)b*TT + t] = s;
}

// ---------------------------------------------------------------------------
// Kernel B (R10 = R6 verified optimum + relaxed barriers).
// R7/R8/R9 established the feasibility corner: (regs/thread) x (waves/SIMD)
// <= ~256, and the serial chain needs 2 waves/SIMD for latency hiding.
// R6's 512-thread, 1-output/thread, ~135-reg layout sits on that corner.
// Only change vs R6: __syncthreads -> lgkm-only barrier (no vmcnt drain),
// keeping the cross-chunk prefetch loads and fAll stores in flight.
// ---------------------------------------------------------------------------
__global__ __launch_bounds__(512, 2) __attribute__((amdgpu_waves_per_eu(2, 2)))
void kMem(
    const float* __restrict__ wAll, const float* __restrict__ fpre,
    const float* __restrict__ eapre,
    const float* __restrict__ f_W, const float* __restrict__ Ge,
    const float* __restrict__ Ga,
    const float* __restrict__ Mv0, const float* __restrict__ ssAll,
    float* __restrict__ fAll)
{
  const int b = blockIdx.x, tid = threadIdx.x;
  const int dd = tid >> 2;               // output index 0..127
  const int kc = tid & 3;                // quad lane: K-slice / m-slice selector
  const int m0 = kc*13;                  // m-chunk base (13,13,13,11 + zero pad)
  const int wslot = (dd >> 5)*36 + (dd & 31);   // padded write position

  // register-resident state & weights
  float mv[13];
  #pragma unroll
  for (int i = 0; i < 13; i++){
    int m = m0 + i;
    mv[i] = (m < MM) ? Mv0[(size_t)m*DD + dd] : 0.f;
  }
  float wf[32], ge[32], ga[32];
  {
    const float4* p;
    p = reinterpret_cast<const float4*>(&f_W[dd*256 + kc*32]);
    #pragma unroll
    for (int i = 0; i < 8; i++){ float4 v = p[i]; wf[4*i]=v.x; wf[4*i+1]=v.y; wf[4*i+2]=v.z; wf[4*i+3]=v.w; }
    p = reinterpret_cast<const float4*>(&Ge[(size_t)dd*DD + kc*32]);
    #pragma unroll
    for (int i = 0; i < 8; i++){ float4 v = p[i]; ge[4*i]=v.x; ge[4*i+1]=v.y; ge[4*i+2]=v.z; ge[4*i+3]=v.w; }
    p = reinterpret_cast<const float4*>(&Ga[(size_t)dd*DD + kc*32]);
    #pragma unroll
    for (int i = 0; i < 8; i++){ float4 v = p[i]; ga[4*i]=v.x; ga[4*i+1]=v.y; ga[4*i+2]=v.z; ga[4*i+3]=v.w; }
  }

  __shared__ __align__(16) float bufR[144];
  __shared__ __align__(16) float bufF[144];
  __shared__ float sW9[9*52];            // rows padded to 52; cols 50,51 == 0
  __shared__ float sS8[8];
  __shared__ __align__(16) float sF8[8*128];
  __shared__ __align__(16) float sEA8[8*256];
  __shared__ __align__(16) float fO8[8*128];

  const size_t base = (size_t)b*TT;
  const int rr0 = tid / 50, mm0 = tid - rr0*50;   // valid when tid < 450

  // zero the pad columns once (publishes never touch cols 50,51)
  if (tid < 18){ int rr = tid >> 1; sW9[rr*52 + 50 + (tid & 1)] = 0.f; }

  // register prefetch of chunk 0
  float4 pF = {0.f,0.f,0.f,0.f}, pEA = {0.f,0.f,0.f,0.f};
  float pW = 0.f, pS = 0.f;
  if (tid < 256) pF = reinterpret_cast<const float4*>(&fpre[base*DD])[tid];
  pEA = reinterpret_cast<const float4*>(&eapre[base*256])[tid];
  if (tid < 450) pW = wAll[(base + rr0)*MM + mm0];
  if (tid < 8)  pS = ssAll[base + tid];

  float wreg[13];   // w_t for the current step (rotated from wnxt)

  for (int ch = 0; ch < TT/8; ch++){
    const int t0 = ch*8;
    if (ch){
      if (tid < 256){
        float4 v = reinterpret_cast<const float4*>(fO8)[tid];
        reinterpret_cast<float4*>(&fAll[(base + t0 - 8)*DD])[tid] = v;
      }
    }
    if (tid < 256) reinterpret_cast<float4*>(sF8)[tid] = pF;
    reinterpret_cast<float4*>(sEA8)[tid] = pEA;
    if (tid < 450) sW9[rr0*52 + mm0] = pW;
    if (tid < 8) sS8[tid] = pS;
    if (t0 + 8 < TT){
      if (tid < 256) pF = reinterpret_cast<const float4*>(&fpre[(base + t0 + 8)*DD])[tid];
      pEA = reinterpret_cast<const float4*>(&eapre[(base + t0 + 8)*256])[tid];
      if (tid < 450) pW = (t0 + 8 + rr0 < TT) ? wAll[(base + t0 + 8 + rr0)*MM + mm0] : 0.f;
      if (tid < 8) pS = ssAll[base + t0 + 8 + tid];
    }
    barL_();   // R: chunk published

    if (ch == 0){
      // bootstrap: wreg = w_0 ; read_0 = sum_m w_0[m]*Mv0[m][dd]
      #pragma unroll
      for (int i = 0; i < 13; i++) wreg[i] = sW9[m0 + i];
      float r = 0.f;
      #pragma unroll
      for (int i = 0; i < 13; i++) r += wreg[i]*mv[i];
      r = quadSum_(r);
      if (kc == 0) bufR[wslot] = r;
      barL_();
    }

    #pragma unroll
    for (int tc = 0; tc < 8; tc++){
      // w_{t+1} (row tc+1; row 8 == next chunk's row 0, so rotation survives
      // the chunk boundary — sW9 is re-published only after these reads)
      float wn[13];
      #pragma unroll
      for (int i = 0; i < 13; i++) wn[i] = sW9[(tc+1)*52 + m0 + i];

      // ---- stage F: f = tanh(read @ f_Wr.T + fpre); r0/r1 off-path ----
      float r0 = 0.f, r1 = 0.f;
      {
        const float4* x4 = reinterpret_cast<const float4*>(&bufR[kc*36]);
        float a0=0.f,a1=0.f,a2=0.f,a3=0.f;
        #pragma unroll
        for (int i = 0; i < 8; i++){
          float4 xv = x4[i];
          a0 += xv.x*wf[4*i]; a1 += xv.y*wf[4*i+1]; a2 += xv.z*wf[4*i+2]; a3 += xv.w*wf[4*i+3];
        }
        #pragma unroll
        for (int i = 0; i < 13; i++){
          r0 += wn[i]*mv[i];
          r1 += (wn[i]*wreg[i])*mv[i];
        }
        float s = quadSum_((a0+a1)+(a2+a3));
        float fval = fast_tanh_(s + sF8[tc*128 + dd]);
        if (kc == 0){
          bufF[wslot] = fval;
          fO8[tc*128 + dd] = fval;
        }
        r0 = quadSum_(r0); r1 = quadSum_(r1);
      }
      barL_();   // B

      // ---- stage EA: e,a from f; read_{t+1}; mv update ----
      {
        const float4* x4 = reinterpret_cast<const float4*>(&bufF[kc*36]);
        float e0=0.f,e1=0.f,g0=0.f,g1=0.f;
        #pragma unroll
        for (int i = 0; i < 8; i++){
          float4 xv = x4[i];
          e0 += xv.x*ge[4*i];   e1 += xv.y*ge[4*i+1];
          e0 += xv.z*ge[4*i+2]; e1 += xv.w*ge[4*i+3];
          g0 += xv.x*ga[4*i];   g1 += xv.y*ga[4*i+1];
          g0 += xv.z*ga[4*i+2]; g1 += xv.w*ga[4*i+3];
        }
        float ep = quadSum_(e0 + e1);
        float ap = quadSum_(g0 + g1);
        float e_d = fast_sig_(ep + sEA8[tc*256 + dd]);
        float a_d = fast_tanh_(ap + sEA8[tc*256 + 128 + dd]);
        if (kc == 0) bufR[wslot] = r0 - e_d*r1 + a_d*sS8[tc];   // read_{t+1}
        #pragma unroll
        for (int i = 0; i < 13; i++){
          float wv = wreg[i];
          mv[i] = mv[i]*(1.f - wv*e_d) + wv*a_d;
        }
      }
      #pragma unroll
      for (int i = 0; i < 13; i++) wreg[i] = wn[i];   // free under full unroll
      barL_();   // C
    }
  }

  if (tid < 256){
    float4 v = reinterpret_cast<const float4*>(fO8)[tid];
    reinterpret_cast<float4*>(&fAll[(base + TT - 8)*DD])[tid] = v;
  }
}

// ---------------------------------------------------------------------------
// Kernel D: gpre GEMM (unchanged).
// ---------------------------------------------------------------------------
__global__ __launch_bounds__(256) void kGate(
    const float* __restrict__ fAll, const float* __restrict__ Wih,
    const float* __restrict__ bih, const float* __restrict__ bhh,
    float* __restrict__ gpre)
{
  const int jt = blockIdx.x;
  const int rt = blockIdx.y;
  const int tid = threadIdx.x;
  __shared__ float sW[64*129];
  __shared__ float sF[32*129];
  for (int i = tid; i < 64*128; i += 256){
    int jj = i >> 7, k = i & 127;
    sW[jj*129 + k] = Wih[(size_t)(jt*64 + jj)*128 + k];
  }
  for (int i = tid; i < 32*128; i += 256){
    int rr = i >> 7, k = i & 127;
    sF[rr*129 + k] = fAll[(size_t)(rt*32 + rr)*128 + k];
  }
  __syncthreads();
  const int jq = tid & 31, rq = tid >> 5;
  float acc[4][2];
  #pragma unroll
  for (int a = 0; a < 4; a++){ acc[a][0] = 0.f; acc[a][1] = 0.f; }
  for (int k = 0; k < 128; k++){
    float fv[4], wv[2];
    #pragma unroll
    for (int a = 0; a < 4; a++) fv[a] = sF[(rq*4 + a)*129 + k];
    wv[0] = sW[(jq*2 + 0)*129 + k];
    wv[1] = sW[(jq*2 + 1)*129 + k];
    #pragma unroll
    for (int a = 0; a < 4; a++){ acc[a][0] += fv[a]*wv[0]; acc[a][1] += fv[a]*wv[1]; }
  }
  #pragma unroll
  for (int a = 0; a < 4; a++){
    int rowi = rt*32 + rq*4 + a;
    #pragma unroll
    for (int c = 0; c < 2; c++){
      int j = jt*64 + jq*2 + c;
      gpre[(size_t)rowi*512 + j] = acc[a][c] + bih[j] + bhh[j];
    }
  }
}

// ---------------------------------------------------------------------------
// Kernel C (R8 structure): LSTM with LDS ring + relaxed per-step barriers.
// Full __syncthreads at chunk boundaries drains prev chunk's Hh/Ch stores,
// making the global skip-loads (pv < chunk start) safe.
// ---------------------------------------------------------------------------
__global__ __launch_bounds__(512, 2) __attribute__((amdgpu_waves_per_eu(2, 2)))
void kLstm(
    const float* __restrict__ gpre, const int* __restrict__ prevA,
    const float* __restrict__ Whh,
    float* __restrict__ Hh, float* __restrict__ Ch)
{
  const int b = blockIdx.x, tid = threadIdx.x;
  const int jo = tid >> 2, kc = tid & 3;
  const int wslot = (jo >> 5)*36 + (jo & 31);

  float whh[4][32];
  #pragma unroll
  for (int g = 0; g < 4; g++){
    const float4* W4 = reinterpret_cast<const float4*>(&Whh[(size_t)(g*128 + jo)*128 + kc*32]);
    #pragma unroll
    for (int i = 0; i < 8; i++){
      float4 v = W4[i];
      whh[g][4*i] = v.x; whh[g][4*i+1] = v.y; whh[g][4*i+2] = v.z; whh[g][4*i+3] = v.w;
    }
  }

  __shared__ __align__(16) float xh[2][144];   // padded h_in broadcast (double buffer)
  __shared__ __align__(16) float gbuf[8*512];  // 16 KB gpre chunk
  __shared__ int spv[TT];
  __shared__ float hRing[8*128];               // last-8-steps h (in-chunk skips)
  __shared__ float cRing[8*128];

  const size_t base = (size_t)b*TT;
  float4 gr0, gr1;
  {
    const float4* g0 = reinterpret_cast<const float4*>(&gpre[base*512]);
    gr0 = g0[tid*2]; gr1 = g0[tid*2+1];
    spv[tid] = prevA[base + tid];
    if (tid < DD) xh[0][(tid >> 5)*36 + (tid & 31)] = 0.f;
  }

  float cin_cur = 0.f;

  for (int ch = 0; ch < TT/8; ch++){
    const int t0 = ch*8;
    if (ch) __syncthreads();           // FULL: drains prev chunk's Hh/Ch stores
    {
      float4* gb4 = reinterpret_cast<float4*>(gbuf);
      gb4[tid*2] = gr0; gb4[tid*2+1] = gr1;
      if (t0 + 8 < TT){
        const float4* gp4 = reinterpret_cast<const float4*>(&gpre[(base + t0 + 8)*512]);
        gr0 = gp4[tid*2]; gr1 = gp4[tid*2+1];
      }
    }
    barL_();                           // chunk published (+ xh ready for tc=0)

    #pragma unroll
    for (int tc = 0; tc < 8; tc++){
      const int t = t0 + tc, p = t & 1;
      if (tc) barL_();                 // xh[p] + ring ready

      int pv2 = -1; float preH = 0.f, preC = 0.f;
      if (t + 1 < TT){
        pv2 = spv[t + 1];
        if (pv2 >= 0 && pv2 < t){
          if (pv2 >= t0){              // in-chunk: LDS ring (barrier-ordered)
            preH = hRing[(pv2 & 7)*128 + jo];
            preC = cRing[(pv2 & 7)*128 + jo];
          } else {                     // older chunk: global, drained at boundary
            preH = Hh[(base + pv2)*DD + jo];
            preC = Ch[(base + pv2)*DD + jo];
          }
        }
      }

      float gp0 = gbuf[tc*512 + jo];
      float gp1 = gbuf[tc*512 + 128 + jo];
      float gp2 = gbuf[tc*512 + 256 + jo];
      float gp3 = gbuf[tc*512 + 384 + jo];

      float a0=0.f,a1=0.f,a2=0.f,a3=0.f;
      {
        const float4* x4 = reinterpret_cast<const float4*>(&xh[p][kc*36]);
        #pragma unroll
        for (int i = 0; i < 8; i++){
          float4 xv = x4[i];
          a0 += xv.x*whh[0][4*i]; a0 += xv.y*whh[0][4*i+1]; a0 += xv.z*whh[0][4*i+2]; a0 += xv.w*whh[0][4*i+3];
          a1 += xv.x*whh[1][4*i]; a1 += xv.y*whh[1][4*i+1]; a1 += xv.z*whh[1][4*i+2]; a1 += xv.w*whh[1][4*i+3];
          a2 += xv.x*whh[2][4*i]; a2 += xv.y*whh[2][4*i+1]; a2 += xv.z*whh[2][4*i+2]; a2 += xv.w*whh[2][4*i+3];
          a3 += xv.x*whh[3][4*i]; a3 += xv.y*whh[3][4*i+1]; a3 += xv.z*whh[3][4*i+2]; a3 += xv.w*whh[3][4*i+3];
        }
      }
      a0 = quadSum_(a0); a1 = quadSum_(a1); a2 = quadSum_(a2); a3 = quadSum_(a3);

      const float ig = gp0 + a0, fg = gp1 + a1, gg = gp2 + a2, og = gp3 + a3;
      const float cn = fast_sig_(fg)*cin_cur + fast_sig_(ig)*fast_tanh_(gg);
      const float hn = fast_sig_(og)*fast_tanh_(cn);

      if (kc == 0){
        Hh[(base + t)*DD + jo] = hn;
        Ch[(base + t)*DD + jo] = cn;
        hRing[(t & 7)*128 + jo] = hn;
        cRing[(t & 7)*128 + jo] = cn;
      }

      float hin_n, cin_n;
      if (pv2 < 0 || pv2 >= t){ hin_n = hn; cin_n = cn; }       // carry
      else                     { hin_n = preH; cin_n = preC; }   // skip
      if (kc == 0) xh[1 - p][wslot] = hin_n;
      cin_cur = cin_n;
    }
  }
}

// ---------------------------------------------------------------------------
// Kernel E: output head (unchanged).
// ---------------------------------------------------------------------------
__global__ __launch_bounds__(256) void kOut(
    const float* __restrict__ Hh, const float* __restrict__ p_W,
    const float* __restrict__ p_b, float* __restrict__ out)
{
  const int row = blockIdx.x*16 + (threadIdx.x >> 4);
  const int l = threadIdx.x & 15;
  const float4* h4 = reinterpret_cast<const float4*>(&Hh[(size_t)row*DD + l*8]);
  const float4* w4 = reinterpret_cast<const float4*>(&p_W[l*8]);
  float4 ha = h4[0], hb = h4[1], wa = w4[0], wb = w4[1];
  float s = ha.x*wa.x + ha.y*wa.y + ha.z*wa.z + ha.w*wa.w
          + hb.x*wb.x + hb.y*wb.y + hb.z*wb.z + hb.w*wb.w;
  s += __shfl_xor(s, 1); s += __shfl_xor(s, 2);
  s += __shfl_xor(s, 4); s += __shfl_xor(s, 8);
  if (l == 0) out[row] = sigmoidf_(s + p_b[0]);
}

// ---------------------------------------------------------------------------
// Launch.
// ---------------------------------------------------------------------------
extern "C" void kernel_launch(void* const* d_in, const int* in_sizes, int n_in,
                              void* d_out, int out_size, void* d_ws, size_t ws_size,
                              hipStream_t stream) {
  const int*   q     = (const int*)  d_in[0];
  const int*   r     = (const int*)  d_in[1];
  const float* k_emb = (const float*)d_in[2];
  const float* Mk    = (const float*)d_in[3];
  const float* Mv0   = (const float*)d_in[4];
  const float* f_W   = (const float*)d_in[5];
  const float* f_b   = (const float*)d_in[6];
  const float* a_W   = (const float*)d_in[7];
  const float* a_b   = (const float*)d_in[8];
  const float* e_W   = (const float*)d_in[9];
  const float* e_b   = (const float*)d_in[10];
  const float* add_W = (const float*)d_in[11];
  const float* add_b = (const float*)d_in[12];
  const float* Wih   = (const float*)d_in[13];
  const float* Whh   = (const float*)d_in[14];
  const float* bih   = (const float*)d_in[15];
  const float* bhh   = (const float*)d_in[16];
  const float* p_W   = (const float*)d_in[17];
  const float* p_b   = (const float*)d_in[18];
  float* out = (float*)d_out;

  char* ws = (char*)d_ws;
  size_t off = 0;
  auto alloc = [&](size_t bytes) -> char* {
    char* p = ws + off;
    off += (bytes + 255) & ~(size_t)255;
    return p;
  };
  float* wAll  = (float*)alloc((size_t)BB*TT*MM*4);
  float* fpre  = (float*)alloc((size_t)BB*TT*DD*4);
  float* ypre  = (float*)alloc((size_t)BB*TT*DD*4);
  float* fAll  = (float*)alloc((size_t)BB*TT*DD*4);
  float* gpre  = (float*)alloc((size_t)BB*TT*512*4);
  float* Hh    = (float*)alloc((size_t)BB*TT*DD*4);
  float* Ch    = (float*)alloc((size_t)BB*TT*DD*4);
  ull*   keyLo = (ull*)  alloc((size_t)BB*TT*8);
  ull*   keyHi = (ull*)  alloc((size_t)BB*TT*8);
  int*   prevA = (int*)  alloc((size_t)BB*TT*4);
  float* Ge    = (float*)alloc((size_t)DD*DD*4);
  float* Ga    = (float*)alloc((size_t)DD*DD*4);
  float* ssAll = (float*)alloc((size_t)BB*TT*4);
  // eapre aliases gpre: lifetimes are disjoint
  // (eapre: [kEA, kMem]; gpre: [kGate, kLstm]).
  float* eapre = gpre;
  (void)ws_size; (void)in_sizes; (void)n_in; (void)out_size;

  kPre  <<<dim3(16, 32), 256, 0, stream>>>(q, r, k_emb, Mk, f_W, f_b, a_W, a_b,
                                           wAll, keyLo, keyHi, fpre, ypre);
  kWW   <<<128, 128, 0, stream>>>(e_W, add_W, a_W, Ge, Ga);
  kEA   <<<dim3(4, 512), 256, 0, stream>>>(ypre, e_W, add_W, e_b, add_b, eapre);
  kSS   <<<32, 512, 0, stream>>>(wAll, ssAll);
  kMatch<<<32, 512, 0, stream>>>(keyLo, keyHi, prevA);
  kMem  <<<32, 512, 0, stream>>>(wAll, fpre, eapre, f_W, Ge, Ga, Mv0, ssAll, fAll);
  kGate <<<dim3(8, 512), 256, 0, stream>>>(fAll, Wih, bih, bhh, gpre);
  kLstm <<<32, 512, 0, stream>>>(gpre, prevA, Whh, Hh, Ch);
  kOut  <<<(BB*TT)/16, 256, 0, stream>>>(Hh, p_W, p_b, out);
}

// Round 7
// 1133.892 us; speedup vs baseline: 2.9197x; 1.0813x over previous
//
#include <hip/hip_runtime.h>
#include <cstdint>
#include <cstddef>

// Problem constants
#define NUM_C 4096
#define BB 32
#define TT 512
#define DD 128
#define MM 50

using ull = unsigned long long;

__device__ __forceinline__ float sigmoidf_(float x){ return 1.0f/(1.0f + expf(-x)); }

// Fast transcendentals on the serial critical path: v_exp_f32 / v_rcp_f32
__device__ __forceinline__ float fexp2_(float x){ return __builtin_amdgcn_exp2f(x); }
__device__ __forceinline__ float frcp_(float x){ return __builtin_amdgcn_rcpf(x); }
__device__ __forceinline__ float fast_sig_(float x){
  return frcp_(1.0f + fexp2_(-1.44269504088896341f*x));
}
__device__ __forceinline__ float fast_tanh_(float x){
  float t = fexp2_(2.88539008177792681f*x);     // e^(2x)
  return 1.0f - 2.0f*frcp_(t + 1.0f);
}

// Quad reduction via DPP (VALU pipe, no LDS): sum over lanes {x, x^1, x^2, x^3}
__device__ __forceinline__ float quadSum_(float v){
  int t = __builtin_amdgcn_update_dpp(0, __float_as_int(v), 0xB1, 0xF, 0xF, true);
  v += __int_as_float(t);
  t = __builtin_amdgcn_update_dpp(0, __float_as_int(v), 0x4E, 0xF, 0xF, true);
  v += __int_as_float(t);
  return v;
}

// Relaxed barrier: LDS visibility only (no vmcnt/expcnt drain). Safe when no
// intra-kernel global-memory RAW across the barrier. Keeps global prefetch
// loads and stores in flight across steps.
__device__ __forceinline__ void barL_(){
  asm volatile("s_waitcnt lgkmcnt(0)\n\ts_barrier" ::: "memory");
}

// ---------------------------------------------------------------------------
// Kernel A: parallel precompute (unchanged).
// ---------------------------------------------------------------------------
__global__ __launch_bounds__(256) void kPre(
    const int* __restrict__ q, const int* __restrict__ r,
    const float* __restrict__ k_emb, const float* __restrict__ Mk,
    const float* __restrict__ f_W, const float* __restrict__ f_b,
    const float* __restrict__ a_W, const float* __restrict__ a_b,
    float* __restrict__ wAll, ull* __restrict__ keyLo, ull* __restrict__ keyHi,
    float* __restrict__ fpre, float* __restrict__ ypre)
{
  const int b = blockIdx.y, t0 = blockIdx.x * 32, tid = threadIdx.x;
  __shared__ __align__(16) float sK[32*129];
  __shared__ int sQ[32];
  __shared__ int sR[32];
  __shared__ union UU {
    struct { float sMk[MM*129]; double sZ[32*MM]; } p2;
    float sW2[128*65];
  } u;

  if (tid < 32){ sQ[tid] = q[b*TT + t0 + tid]; sR[tid] = r[b*TT + t0 + tid]; }
  __syncthreads();
  for (int i = tid; i < 32*128; i += 256){
    int tl = i >> 7, j = i & 127;
    sK[tl*129 + j] = k_emb[(size_t)sQ[tl]*DD + j];
  }
  for (int i = tid; i < MM*128; i += 256){
    int m = i >> 7, j = i & 127;
    u.p2.sMk[m*129 + j] = Mk[i];
  }
  __syncthreads();

  for (int idx = tid; idx < 32*MM; idx += 256){
    int tl = idx / MM, m = idx - tl*MM;
    double z = 0.0;
    for (int j = 0; j < DD; j++)
      z += (double)sK[tl*129 + j] * (double)u.p2.sMk[m*129 + j];
    u.p2.sZ[tl*MM + m] = z;
  }
  __syncthreads();

  {
    int tl = tid >> 3, l8 = tid & 7;
    double zmax = -1e300;
    for (int m = l8; m < MM; m += 8) zmax = fmax(zmax, u.p2.sZ[tl*MM + m]);
    for (int s = 1; s < 8; s <<= 1) zmax = fmax(zmax, __shfl_xor(zmax, s));
    double se = 0.0;
    for (int m = l8; m < MM; m += 8){
      double e = exp(u.p2.sZ[tl*MM + m] - zmax);
      u.p2.sZ[tl*MM + m] = e;
      se += e;
    }
    for (int s = 1; s < 8; s <<= 1) se += __shfl_xor(se, s);
    double inv = 1.0 / se;
    ull klo = 0, khi = 0;
    for (int m = l8; m < MM; m += 8){
      double w = u.p2.sZ[tl*MM + m] * inv;
      wAll[((size_t)(b*TT + t0 + tl))*MM + m] = (float)w;
      double tw = fmin((w - 0.075)/(0.088 - 0.075), (1.0 - w)/(1.0 - 0.088));
      tw = fmax(tw, 0.0);
      ull iv = (tw >= 0.6) ? 2ull : ((tw >= 0.1) ? 1ull : 0ull);
      if (m < 32) klo |= iv << (2*m); else khi |= iv << (2*(m-32));
    }
    for (int s = 1; s < 8; s <<= 1){ klo |= __shfl_xor(klo, s); khi |= __shfl_xor(khi, s); }
    if (l8 == 0){ keyLo[b*TT + t0 + tl] = klo; keyHi[b*TT + t0 + tl] = khi; }
  }

  {
    const int dq = tid & 31, tq = tid >> 5;
    float acc[4][4];
    #pragma unroll
    for (int a = 0; a < 4; a++){ acc[a][0]=0.f; acc[a][1]=0.f; acc[a][2]=0.f; acc[a][3]=0.f; }
    for (int jh = 0; jh < 2; jh++){
      __syncthreads();
      for (int i = tid; i < 128*64; i += 256){
        int dd = i >> 6, jj = i & 63;
        u.sW2[dd*65 + jj] = f_W[dd*256 + 128 + jh*64 + jj];
      }
      __syncthreads();
      for (int jj = 0; jj < 64; jj++){
        float kv[4], wv[4];
        #pragma unroll
        for (int a = 0; a < 4; a++) kv[a] = sK[(tq*4 + a)*129 + jh*64 + jj];
        #pragma unroll
        for (int c = 0; c < 4; c++) wv[c] = u.sW2[(dq*4 + c)*65 + jj];
        #pragma unroll
        for (int a = 0; a < 4; a++){
          acc[a][0] += kv[a]*wv[0]; acc[a][1] += kv[a]*wv[1];
          acc[a][2] += kv[a]*wv[2]; acc[a][3] += kv[a]*wv[3];
        }
      }
    }
    #pragma unroll
    for (int a = 0; a < 4; a++){
      int tl = tq*4 + a;
      #pragma unroll
      for (int c = 0; c < 4; c++){
        int d = dq*4 + c;
        fpre[((size_t)(b*TT + t0 + tl))*DD + d] = acc[a][c] + f_b[d];
      }
    }
  }

  for (int i = tid; i < 32*DD; i += 256){
    int tl = i >> 7, d = i & 127;
    ypre[((size_t)(b*TT + t0 + tl))*DD + d] =
        a_W[(size_t)d*(NUM_C + DD) + sQ[tl]] * (float)sR[tl] + a_b[d];
  }
}

// ---------------------------------------------------------------------------
// Kernel A2: exact match search (unchanged).
// ---------------------------------------------------------------------------
__global__ __launch_bounds__(512) void kMatch(
    const ull* __restrict__ keyLo, const ull* __restrict__ keyHi, int* __restrict__ prevA)
{
  const int b = blockIdx.x, i = threadIdx.x;
  __shared__ ull slo[TT];
  __shared__ ull shi[TT];
  slo[i] = keyLo[b*TT + i];
  shi[i] = keyHi[b*TT + i];
  __syncthreads();
  const ull mylo = slo[i], myhi = shi[i];
  int found = -1;
  for (int j = i - 1; j >= 0; j--){
    if (slo[j] == mylo && shi[j] == myhi){ found = j; break; }
  }
  prevA[b*TT + i] = found;
}

// ---------------------------------------------------------------------------
// Kernel W: one-time weight products (unchanged).
// ---------------------------------------------------------------------------
__global__ __launch_bounds__(128) void kWW(
    const float* __restrict__ e_W, const float* __restrict__ add_W,
    const float* __restrict__ a_W,
    float* __restrict__ Ge, float* __restrict__ Ga)
{
  const int d = blockIdx.x;    // 0..127
  const int k = threadIdx.x;   // 0..127
  __shared__ float se[128];
  __shared__ float sa[128];
  se[k] = e_W[(size_t)d*DD + k];
  sa[k] = add_W[(size_t)d*DD + k];
  __syncthreads();
  float ge = 0.f, ga = 0.f;
  for (int j = 0; j < DD; j++){
    float af = a_W[(size_t)j*(NUM_C + DD) + NUM_C + k];
    ge += se[j]*af;
    ga += sa[j]*af;
  }
  Ge[(size_t)d*DD + k] = ge;
  Ga[(size_t)d*DD + k] = ga;
}

// ---------------------------------------------------------------------------
// Kernel EA: eapre GEMM (unchanged).
// ---------------------------------------------------------------------------
__global__ __launch_bounds__(256) void kEA(
    const float* __restrict__ ypre, const float* __restrict__ e_W,
    const float* __restrict__ add_W, const float* __restrict__ e_b,
    const float* __restrict__ add_b, float* __restrict__ eapre)
{
  const int jt = blockIdx.x;   // 0..3  (64 output cols each)
  const int rt = blockIdx.y;   // 0..511 (32 rows each)
  const int tid = threadIdx.x;
  __shared__ float sW[64*129];
  __shared__ float sF[32*129];
  for (int i = tid; i < 64*128; i += 256){
    int jj = i >> 7, k = i & 127;
    int j = jt*64 + jj;
    sW[jj*129 + k] = (j < 128) ? e_W[(size_t)j*DD + k] : add_W[(size_t)(j-128)*DD + k];
  }
  for (int i = tid; i < 32*128; i += 256){
    int rr = i >> 7, k = i & 127;
    sF[rr*129 + k] = ypre[(size_t)(rt*32 + rr)*DD + k];
  }
  __syncthreads();
  const int jq = tid & 31, rq = tid >> 5;
  float acc[4][2];
  #pragma unroll
  for (int a = 0; a < 4; a++){ acc[a][0] = 0.f; acc[a][1] = 0.f; }
  for (int k = 0; k < 128; k++){
    float fv[4], wv[2];
    #pragma unroll
    for (int a = 0; a < 4; a++) fv[a] = sF[(rq*4 + a)*129 + k];
    wv[0] = sW[(jq*2 + 0)*129 + k];
    wv[1] = sW[(jq*2 + 1)*129 + k];
    #pragma unroll
    for (int a = 0; a < 4; a++){ acc[a][0] += fv[a]*wv[0]; acc[a][1] += fv[a]*wv[1]; }
  }
  #pragma unroll
  for (int a = 0; a < 4; a++){
    int rowi = rt*32 + rq*4 + a;
    #pragma unroll
    for (int c = 0; c < 2; c++){
      int j = jt*64 + jq*2 + c;
      float bj = (j < 128) ? e_b[j] : add_b[j - 128];
      eapre[(size_t)rowi*256 + j] = acc[a][c] + bj;
    }
  }
}

// ---------------------------------------------------------------------------
// Kernel B (R11): R10 + post-update read.
// The r0/r1/ss read-decomposition (R5 relic) is replaced by the direct form
//   read_{t+1}[dd] = sum_m w_{t+1}[m] * mv_new[m][dd]
// computed right after the mv update in stage EA (mv_new is available there).
// Saves ~44 VALU ops/step (kMem is ~74% issue-bound on active CUs) and
// deletes kSS/ssAll entirely. mv update uses the 2-op form
//   mv += w*(a - e*mv). Matches the reference dataflow (einsum after update).
// ---------------------------------------------------------------------------
__global__ __launch_bounds__(512, 2) __attribute__((amdgpu_waves_per_eu(2, 2)))
void kMem(
    const float* __restrict__ wAll, const float* __restrict__ fpre,
    const float* __restrict__ eapre,
    const float* __restrict__ f_W, const float* __restrict__ Ge,
    const float* __restrict__ Ga,
    const float* __restrict__ Mv0,
    float* __restrict__ fAll)
{
  const int b = blockIdx.x, tid = threadIdx.x;
  const int dd = tid >> 2;               // output index 0..127
  const int kc = tid & 3;                // quad lane: K-slice / m-slice selector
  const int m0 = kc*13;                  // m-chunk base (13,13,13,11 + zero pad)
  const int wslot = (dd >> 5)*36 + (dd & 31);   // padded write position

  // register-resident state & weights
  float mv[13];
  #pragma unroll
  for (int i = 0; i < 13; i++){
    int m = m0 + i;
    mv[i] = (m < MM) ? Mv0[(size_t)m*DD + dd] : 0.f;
  }
  float wf[32], ge[32], ga[32];
  {
    const float4* p;
    p = reinterpret_cast<const float4*>(&f_W[dd*256 + kc*32]);
    #pragma unroll
    for (int i = 0; i < 8; i++){ float4 v = p[i]; wf[4*i]=v.x; wf[4*i+1]=v.y; wf[4*i+2]=v.z; wf[4*i+3]=v.w; }
    p = reinterpret_cast<const float4*>(&Ge[(size_t)dd*DD + kc*32]);
    #pragma unroll
    for (int i = 0; i < 8; i++){ float4 v = p[i]; ge[4*i]=v.x; ge[4*i+1]=v.y; ge[4*i+2]=v.z; ge[4*i+3]=v.w; }
    p = reinterpret_cast<const float4*>(&Ga[(size_t)dd*DD + kc*32]);
    #pragma unroll
    for (int i = 0; i < 8; i++){ float4 v = p[i]; ga[4*i]=v.x; ga[4*i+1]=v.y; ga[4*i+2]=v.z; ga[4*i+3]=v.w; }
  }

  __shared__ __align__(16) float bufR[144];
  __shared__ __align__(16) float bufF[144];
  __shared__ float sW9[9*52];            // rows padded to 52; cols 50,51 == 0
  __shared__ __align__(16) float sF8[8*128];
  __shared__ __align__(16) float sEA8[8*256];
  __shared__ __align__(16) float fO8[8*128];

  const size_t base = (size_t)b*TT;
  const int rr0 = tid / 50, mm0 = tid - rr0*50;   // valid when tid < 450

  // zero the pad columns once (publishes never touch cols 50,51)
  if (tid < 18){ int rr = tid >> 1; sW9[rr*52 + 50 + (tid & 1)] = 0.f; }

  // register prefetch of chunk 0
  float4 pF = {0.f,0.f,0.f,0.f}, pEA = {0.f,0.f,0.f,0.f};
  float pW = 0.f;
  if (tid < 256) pF = reinterpret_cast<const float4*>(&fpre[base*DD])[tid];
  pEA = reinterpret_cast<const float4*>(&eapre[base*256])[tid];
  if (tid < 450) pW = wAll[(base + rr0)*MM + mm0];

  float wreg[13];   // w_t for the current step (rotated from wn)

  for (int ch = 0; ch < TT/8; ch++){
    const int t0 = ch*8;
    if (ch){
      if (tid < 256){
        float4 v = reinterpret_cast<const float4*>(fO8)[tid];
        reinterpret_cast<float4*>(&fAll[(base + t0 - 8)*DD])[tid] = v;
      }
    }
    if (tid < 256) reinterpret_cast<float4*>(sF8)[tid] = pF;
    reinterpret_cast<float4*>(sEA8)[tid] = pEA;
    if (tid < 450) sW9[rr0*52 + mm0] = pW;
    if (t0 + 8 < TT){
      if (tid < 256) pF = reinterpret_cast<const float4*>(&fpre[(base + t0 + 8)*DD])[tid];
      pEA = reinterpret_cast<const float4*>(&eapre[(base + t0 + 8)*256])[tid];
      if (tid < 450) pW = (t0 + 8 + rr0 < TT) ? wAll[(base + t0 + 8 + rr0)*MM + mm0] : 0.f;
    }
    barL_();   // R: chunk published

    if (ch == 0){
      // bootstrap: wreg = w_0 ; read_0 = sum_m w_0[m]*Mv0[m][dd]
      #pragma unroll
      for (int i = 0; i < 13; i++) wreg[i] = sW9[m0 + i];
      float r = 0.f;
      #pragma unroll
      for (int i = 0; i < 13; i++) r += wreg[i]*mv[i];
      r = quadSum_(r);
      if (kc == 0) bufR[wslot] = r;
      barL_();
    }

    #pragma unroll
    for (int tc = 0; tc < 8; tc++){
      // w_{t+1} (row tc+1; row 8 == next chunk's row 0, so rotation survives
      // the chunk boundary — sW9 is re-published only after these reads)
      float wn[13];
      #pragma unroll
      for (int i = 0; i < 13; i++) wn[i] = sW9[(tc+1)*52 + m0 + i];

      // ---- stage F: f = tanh(read @ f_Wr.T + fpre) ----
      {
        const float4* x4 = reinterpret_cast<const float4*>(&bufR[kc*36]);
        float a0=0.f,a1=0.f,a2=0.f,a3=0.f;
        #pragma unroll
        for (int i = 0; i < 8; i++){
          float4 xv = x4[i];
          a0 += xv.x*wf[4*i]; a1 += xv.y*wf[4*i+1]; a2 += xv.z*wf[4*i+2]; a3 += xv.w*wf[4*i+3];
        }
        float s = quadSum_((a0+a1)+(a2+a3));
        float fval = fast_tanh_(s + sF8[tc*128 + dd]);
        if (kc == 0){
          bufF[wslot] = fval;
          fO8[tc*128 + dd] = fval;
        }
      }
      barL_();   // B

      // ---- stage EA: e,a from f; mv update; read_{t+1} = wn . mv_new ----
      {
        const float4* x4 = reinterpret_cast<const float4*>(&bufF[kc*36]);
        float e0=0.f,e1=0.f,g0=0.f,g1=0.f;
        #pragma unroll
        for (int i = 0; i < 8; i++){
          float4 xv = x4[i];
          e0 += xv.x*ge[4*i];   e1 += xv.y*ge[4*i+1];
          e0 += xv.z*ge[4*i+2]; e1 += xv.w*ge[4*i+3];
          g0 += xv.x*ga[4*i];   g1 += xv.y*ga[4*i+1];
          g0 += xv.z*ga[4*i+2]; g1 += xv.w*ga[4*i+3];
        }
        float ep = quadSum_(e0 + e1);
        float ap = quadSum_(g0 + g1);
        float e_d = fast_sig_(ep + sEA8[tc*256 + dd]);
        float a_d = fast_tanh_(ap + sEA8[tc*256 + 128 + dd]);
        float rp0 = 0.f, rp1 = 0.f;
        #pragma unroll
        for (int i = 0; i < 13; i++){
          float t = __builtin_fmaf(-e_d, mv[i], a_d);   // a - e*mv
          mv[i] = __builtin_fmaf(wreg[i], t, mv[i]);    // mv + w*(a - e*mv)
          if (i & 1) rp1 = __builtin_fmaf(wn[i], mv[i], rp1);
          else       rp0 = __builtin_fmaf(wn[i], mv[i], rp0);
        }
        float rd = quadSum_(rp0 + rp1);
        if (kc == 0) bufR[wslot] = rd;                  // read_{t+1}
      }
      #pragma unroll
      for (int i = 0; i < 13; i++) wreg[i] = wn[i];   // free under full unroll
      barL_();   // C
    }
  }

  if (tid < 256){
    float4 v = reinterpret_cast<const float4*>(fO8)[tid];
    reinterpret_cast<float4*>(&fAll[(base + TT - 8)*DD])[tid] = v;
  }
}

// ---------------------------------------------------------------------------
// Kernel D: gpre GEMM (unchanged).
// ---------------------------------------------------------------------------
__global__ __launch_bounds__(256) void kGate(
    const float* __restrict__ fAll, const float* __restrict__ Wih,
    const float* __restrict__ bih, const float* __restrict__ bhh,
    float* __restrict__ gpre)
{
  const int jt = blockIdx.x;
  const int rt = blockIdx.y;
  const int tid = threadIdx.x;
  __shared__ float sW[64*129];
  __shared__ float sF[32*129];
  for (int i = tid; i < 64*128; i += 256){
    int jj = i >> 7, k = i & 127;
    sW[jj*129 + k] = Wih[(size_t)(jt*64 + jj)*128 + k];
  }
  for (int i = tid; i < 32*128; i += 256){
    int rr = i >> 7, k = i & 127;
    sF[rr*129 + k] = fAll[(size_t)(rt*32 + rr)*128 + k];
  }
  __syncthreads();
  const int jq = tid & 31, rq = tid >> 5;
  float acc[4][2];
  #pragma unroll
  for (int a = 0; a < 4; a++){ acc[a][0] = 0.f; acc[a][1] = 0.f; }
  for (int k = 0; k < 128; k++){
    float fv[4], wv[2];
    #pragma unroll
    for (int a = 0; a < 4; a++) fv[a] = sF[(rq*4 + a)*129 + k];
    wv[0] = sW[(jq*2 + 0)*129 + k];
    wv[1] = sW[(jq*2 + 1)*129 + k];
    #pragma unroll
    for (int a = 0; a < 4; a++){ acc[a][0] += fv[a]*wv[0]; acc[a][1] += fv[a]*wv[1]; }
  }
  #pragma unroll
  for (int a = 0; a < 4; a++){
    int rowi = rt*32 + rq*4 + a;
    #pragma unroll
    for (int c = 0; c < 2; c++){
      int j = jt*64 + jq*2 + c;
      gpre[(size_t)rowi*512 + j] = acc[a][c] + bih[j] + bhh[j];
    }
  }
}

// ---------------------------------------------------------------------------
// Kernel C (unchanged from R10): LSTM with LDS ring + relaxed barriers.
// ---------------------------------------------------------------------------
__global__ __launch_bounds__(512, 2) __attribute__((amdgpu_waves_per_eu(2, 2)))
void kLstm(
    const float* __restrict__ gpre, const int* __restrict__ prevA,
    const float* __restrict__ Whh,
    float* __restrict__ Hh, float* __restrict__ Ch)
{
  const int b = blockIdx.x, tid = threadIdx.x;
  const int jo = tid >> 2, kc = tid & 3;
  const int wslot = (jo >> 5)*36 + (jo & 31);

  float whh[4][32];
  #pragma unroll
  for (int g = 0; g < 4; g++){
    const float4* W4 = reinterpret_cast<const float4*>(&Whh[(size_t)(g*128 + jo)*128 + kc*32]);
    #pragma unroll
    for (int i = 0; i < 8; i++){
      float4 v = W4[i];
      whh[g][4*i] = v.x; whh[g][4*i+1] = v.y; whh[g][4*i+2] = v.z; whh[g][4*i+3] = v.w;
    }
  }

  __shared__ __align__(16) float xh[2][144];   // padded h_in broadcast (double buffer)
  __shared__ __align__(16) float gbuf[8*512];  // 16 KB gpre chunk
  __shared__ int spv[TT];
  __shared__ float hRing[8*128];               // last-8-steps h (in-chunk skips)
  __shared__ float cRing[8*128];

  const size_t base = (size_t)b*TT;
  float4 gr0, gr1;
  {
    const float4* g0 = reinterpret_cast<const float4*>(&gpre[base*512]);
    gr0 = g0[tid*2]; gr1 = g0[tid*2+1];
    spv[tid] = prevA[base + tid];
    if (tid < DD) xh[0][(tid >> 5)*36 + (tid & 31)] = 0.f;
  }

  float cin_cur = 0.f;

  for (int ch = 0; ch < TT/8; ch++){
    const int t0 = ch*8;
    if (ch) __syncthreads();           // FULL: drains prev chunk's Hh/Ch stores
    {
      float4* gb4 = reinterpret_cast<float4*>(gbuf);
      gb4[tid*2] = gr0; gb4[tid*2+1] = gr1;
      if (t0 + 8 < TT){
        const float4* gp4 = reinterpret_cast<const float4*>(&gpre[(base + t0 + 8)*512]);
        gr0 = gp4[tid*2]; gr1 = gp4[tid*2+1];
      }
    }
    barL_();                           // chunk published (+ xh ready for tc=0)

    #pragma unroll
    for (int tc = 0; tc < 8; tc++){
      const int t = t0 + tc, p = t & 1;
      if (tc) barL_();                 // xh[p] + ring ready

      int pv2 = -1; float preH = 0.f, preC = 0.f;
      if (t + 1 < TT){
        pv2 = spv[t + 1];
        if (pv2 >= 0 && pv2 < t){
          if (pv2 >= t0){              // in-chunk: LDS ring (barrier-ordered)
            preH = hRing[(pv2 & 7)*128 + jo];
            preC = cRing[(pv2 & 7)*128 + jo];
          } else {                     // older chunk: global, drained at boundary
            preH = Hh[(base + pv2)*DD + jo];
            preC = Ch[(base + pv2)*DD + jo];
          }
        }
      }

      float gp0 = gbuf[tc*512 + jo];
      float gp1 = gbuf[tc*512 + 128 + jo];
      float gp2 = gbuf[tc*512 + 256 + jo];
      float gp3 = gbuf[tc*512 + 384 + jo];

      float a0=0.f,a1=0.f,a2=0.f,a3=0.f;
      {
        const float4* x4 = reinterpret_cast<const float4*>(&xh[p][kc*36]);
        #pragma unroll
        for (int i = 0; i < 8; i++){
          float4 xv = x4[i];
          a0 += xv.x*whh[0][4*i]; a0 += xv.y*whh[0][4*i+1]; a0 += xv.z*whh[0][4*i+2]; a0 += xv.w*whh[0][4*i+3];
          a1 += xv.x*whh[1][4*i]; a1 += xv.y*whh[1][4*i+1]; a1 += xv.z*whh[1][4*i+2]; a1 += xv.w*whh[1][4*i+3];
          a2 += xv.x*whh[2][4*i]; a2 += xv.y*whh[2][4*i+1]; a2 += xv.z*whh[2][4*i+2]; a2 += xv.w*whh[2][4*i+3];
          a3 += xv.x*whh[3][4*i]; a3 += xv.y*whh[3][4*i+1]; a3 += xv.z*whh[3][4*i+2]; a3 += xv.w*whh[3][4*i+3];
        }
      }
      a0 = quadSum_(a0); a1 = quadSum_(a1); a2 = quadSum_(a2); a3 = quadSum_(a3);

      const float ig = gp0 + a0, fg = gp1 + a1, gg = gp2 + a2, og = gp3 + a3;
      const float cn = fast_sig_(fg)*cin_cur + fast_sig_(ig)*fast_tanh_(gg);
      const float hn = fast_sig_(og)*fast_tanh_(cn);

      if (kc == 0){
        Hh[(base + t)*DD + jo] = hn;
        Ch[(base + t)*DD + jo] = cn;
        hRing[(t & 7)*128 + jo] = hn;
        cRing[(t & 7)*128 + jo] = cn;
      }

      float hin_n, cin_n;
      if (pv2 < 0 || pv2 >= t){ hin_n = hn; cin_n = cn; }       // carry
      else                     { hin_n = preH; cin_n = preC; }   // skip
      if (kc == 0) xh[1 - p][wslot] = hin_n;
      cin_cur = cin_n;
    }
  }
}

// ---------------------------------------------------------------------------
// Kernel E: output head (unchanged).
// ---------------------------------------------------------------------------
__global__ __launch_bounds__(256) void kOut(
    const float* __restrict__ Hh, const float* __restrict__ p_W,
    const float* __restrict__ p_b, float* __restrict__ out)
{
  const int row = blockIdx.x*16 + (threadIdx.x >> 4);
  const int l = threadIdx.x & 15;
  const float4* h4 = reinterpret_cast<const float4*>(&Hh[(size_t)row*DD + l*8]);
  const float4* w4 = reinterpret_cast<const float4*>(&p_W[l*8]);
  float4 ha = h4[0], hb = h4[1], wa = w4[0], wb = w4[1];
  float s = ha.x*wa.x + ha.y*wa.y + ha.z*wa.z + ha.w*wa.w
          + hb.x*wb.x + hb.y*wb.y + hb.z*wb.z + hb.w*wb.w;
  s += __shfl_xor(s, 1); s += __shfl_xor(s, 2);
  s += __shfl_xor(s, 4); s += __shfl_xor(s, 8);
  if (l == 0) out[row] = sigmoidf_(s + p_b[0]);
}

// ---------------------------------------------------------------------------
// Launch.
// ---------------------------------------------------------------------------
extern "C" void kernel_launch(void* const* d_in, const int* in_sizes, int n_in,
                              void* d_out, int out_size, void* d_ws, size_t ws_size,
                              hipStream_t stream) {
  const int*   q     = (const int*)  d_in[0];
  const int*   r     = (const int*)  d_in[1];
  const float* k_emb = (const float*)d_in[2];
  const float* Mk    = (const float*)d_in[3];
  const float* Mv0   = (const float*)d_in[4];
  const float* f_W   = (const float*)d_in[5];
  const float* f_b   = (const float*)d_in[6];
  const float* a_W   = (const float*)d_in[7];
  const float* a_b   = (const float*)d_in[8];
  const float* e_W   = (const float*)d_in[9];
  const float* e_b   = (const float*)d_in[10];
  const float* add_W = (const float*)d_in[11];
  const float* add_b = (const float*)d_in[12];
  const float* Wih   = (const float*)d_in[13];
  const float* Whh   = (const float*)d_in[14];
  const float* bih   = (const float*)d_in[15];
  const float* bhh   = (const float*)d_in[16];
  const float* p_W   = (const float*)d_in[17];
  const float* p_b   = (const float*)d_in[18];
  float* out = (float*)d_out;

  char* ws = (char*)d_ws;
  size_t off = 0;
  auto alloc = [&](size_t bytes) -> char* {
    char* p = ws + off;
    off += (bytes + 255) & ~(size_t)255;
    return p;
  };
  float* wAll  = (float*)alloc((size_t)BB*TT*MM*4);
  float* fpre  = (float*)alloc((size_t)BB*TT*DD*4);
  float* ypre  = (float*)alloc((size_t)BB*TT*DD*4);
  float* fAll  = (float*)alloc((size_t)BB*TT*DD*4);
  float* gpre  = (float*)alloc((size_t)BB*TT*512*4);
  float* Hh    = (float*)alloc((size_t)BB*TT*DD*4);
  float* Ch    = (float*)alloc((size_t)BB*TT*DD*4);
  ull*   keyLo = (ull*)  alloc((size_t)BB*TT*8);
  ull*   keyHi = (ull*)  alloc((size_t)BB*TT*8);
  int*   prevA = (int*)  alloc((size_t)BB*TT*4);
  float* Ge    = (float*)alloc((size_t)DD*DD*4);
  float* Ga    = (float*)alloc((size_t)DD*DD*4);
  // eapre aliases gpre: lifetimes are disjoint
  // (eapre: [kEA, kMem]; gpre: [kGate, kLstm]).
  float* eapre = gpre;
  (void)ws_size; (void)in_sizes; (void)n_in; (void)out_size;

  kPre  <<<dim3(16, 32), 256, 0, stream>>>(q, r, k_emb, Mk, f_W, f_b, a_W, a_b,
                                           wAll, keyLo, keyHi, fpre, ypre);
  kWW   <<<128, 128, 0, stream>>>(e_W, add_W, a_W, Ge, Ga);
  kEA   <<<dim3(4, 512), 256, 0, stream>>>(ypre, e_W, add_W, e_b, add_b, eapre);
  kMatch<<<32, 512, 0, stream>>>(keyLo, keyHi, prevA);
  kMem  <<<32, 512, 0, stream>>>(wAll, fpre, eapre, f_W, Ge, Ga, Mv0, fAll);
  kGate <<<dim3(8, 512), 256, 0, stream>>>(fAll, Wih, bih, bhh, gpre);
  kLstm <<<32, 512, 0, stream>>>(gpre, prevA, Whh, Hh, Ch);
  kOut  <<<(BB*TT)/16, 256, 0, stream>>>(Hh, p_W, p_b, out);
}

// Round 8
// 1045.568 us; speedup vs baseline: 3.1663x; 1.0845x over previous
//
#include <hip/hip_runtime.h>
#include <cstdint>
#include <cstddef>

// Problem constants
#define NUM_C 4096
#define BB 32
#define TT 512
#define DD 128
#define MM 50

using ull = unsigned long long;

__device__ __forceinline__ float sigmoidf_(float x){ return 1.0f/(1.0f + expf(-x)); }

// Fast transcendentals on the serial critical path: v_exp_f32 / v_rcp_f32
__device__ __forceinline__ float fexp2_(float x){ return __builtin_amdgcn_exp2f(x); }
__device__ __forceinline__ float frcp_(float x){ return __builtin_amdgcn_rcpf(x); }
__device__ __forceinline__ float fast_sig_(float x){
  return frcp_(1.0f + fexp2_(-1.44269504088896341f*x));
}
__device__ __forceinline__ float fast_tanh_(float x){
  float t = fexp2_(2.88539008177792681f*x);     // e^(2x)
  return 1.0f - 2.0f*frcp_(t + 1.0f);
}

// Quad reduction via DPP (VALU pipe, no LDS): sum over lanes {x, x^1, x^2, x^3}
__device__ __forceinline__ float quadSum_(float v){
  int t = __builtin_amdgcn_update_dpp(0, __float_as_int(v), 0xB1, 0xF, 0xF, true);
  v += __int_as_float(t);
  t = __builtin_amdgcn_update_dpp(0, __float_as_int(v), 0x4E, 0xF, 0xF, true);
  v += __int_as_float(t);
  return v;
}

// Relaxed barrier: LDS visibility only (no vmcnt/expcnt drain).
__device__ __forceinline__ void barL_(){
  asm volatile("s_waitcnt lgkmcnt(0)\n\ts_barrier" ::: "memory");
}
// Drain this thread's outstanding vector-memory ops (used before publishing
// a cross-block progress flag).
__device__ __forceinline__ void waitVM_(){
  asm volatile("s_waitcnt vmcnt(0)" ::: "memory");
}

// ---------------------------------------------------------------------------
// Kernel A: parallel precompute (unchanged).
// ---------------------------------------------------------------------------
__global__ __launch_bounds__(256) void kPre(
    const int* __restrict__ q, const int* __restrict__ r,
    const float* __restrict__ k_emb, const float* __restrict__ Mk,
    const float* __restrict__ f_W, const float* __restrict__ f_b,
    const float* __restrict__ a_W, const float* __restrict__ a_b,
    float* __restrict__ wAll, ull* __restrict__ keyLo, ull* __restrict__ keyHi,
    float* __restrict__ fpre, float* __restrict__ ypre)
{
  const int b = blockIdx.y, t0 = blockIdx.x * 32, tid = threadIdx.x;
  __shared__ __align__(16) float sK[32*129];
  __shared__ int sQ[32];
  __shared__ int sR[32];
  __shared__ union UU {
    struct { float sMk[MM*129]; double sZ[32*MM]; } p2;
    float sW2[128*65];
  } u;

  if (tid < 32){ sQ[tid] = q[b*TT + t0 + tid]; sR[tid] = r[b*TT + t0 + tid]; }
  __syncthreads();
  for (int i = tid; i < 32*128; i += 256){
    int tl = i >> 7, j = i & 127;
    sK[tl*129 + j] = k_emb[(size_t)sQ[tl]*DD + j];
  }
  for (int i = tid; i < MM*128; i += 256){
    int m = i >> 7, j = i & 127;
    u.p2.sMk[m*129 + j] = Mk[i];
  }
  __syncthreads();

  for (int idx = tid; idx < 32*MM; idx += 256){
    int tl = idx / MM, m = idx - tl*MM;
    double z = 0.0;
    for (int j = 0; j < DD; j++)
      z += (double)sK[tl*129 + j] * (double)u.p2.sMk[m*129 + j];
    u.p2.sZ[tl*MM + m] = z;
  }
  __syncthreads();

  {
    int tl = tid >> 3, l8 = tid & 7;
    double zmax = -1e300;
    for (int m = l8; m < MM; m += 8) zmax = fmax(zmax, u.p2.sZ[tl*MM + m]);
    for (int s = 1; s < 8; s <<= 1) zmax = fmax(zmax, __shfl_xor(zmax, s));
    double se = 0.0;
    for (int m = l8; m < MM; m += 8){
      double e = exp(u.p2.sZ[tl*MM + m] - zmax);
      u.p2.sZ[tl*MM + m] = e;
      se += e;
    }
    for (int s = 1; s < 8; s <<= 1) se += __shfl_xor(se, s);
    double inv = 1.0 / se;
    ull klo = 0, khi = 0;
    for (int m = l8; m < MM; m += 8){
      double w = u.p2.sZ[tl*MM + m] * inv;
      wAll[((size_t)(b*TT + t0 + tl))*MM + m] = (float)w;
      double tw = fmin((w - 0.075)/(0.088 - 0.075), (1.0 - w)/(1.0 - 0.088));
      tw = fmax(tw, 0.0);
      ull iv = (tw >= 0.6) ? 2ull : ((tw >= 0.1) ? 1ull : 0ull);
      if (m < 32) klo |= iv << (2*m); else khi |= iv << (2*(m-32));
    }
    for (int s = 1; s < 8; s <<= 1){ klo |= __shfl_xor(klo, s); khi |= __shfl_xor(khi, s); }
    if (l8 == 0){ keyLo[b*TT + t0 + tl] = klo; keyHi[b*TT + t0 + tl] = khi; }
  }

  {
    const int dq = tid & 31, tq = tid >> 5;
    float acc[4][4];
    #pragma unroll
    for (int a = 0; a < 4; a++){ acc[a][0]=0.f; acc[a][1]=0.f; acc[a][2]=0.f; acc[a][3]=0.f; }
    for (int jh = 0; jh < 2; jh++){
      __syncthreads();
      for (int i = tid; i < 128*64; i += 256){
        int dd = i >> 6, jj = i & 63;
        u.sW2[dd*65 + jj] = f_W[dd*256 + 128 + jh*64 + jj];
      }
      __syncthreads();
      for (int jj = 0; jj < 64; jj++){
        float kv[4], wv[4];
        #pragma unroll
        for (int a = 0; a < 4; a++) kv[a] = sK[(tq*4 + a)*129 + jh*64 + jj];
        #pragma unroll
        for (int c = 0; c < 4; c++) wv[c] = u.sW2[(dq*4 + c)*65 + jj];
        #pragma unroll
        for (int a = 0; a < 4; a++){
          acc[a][0] += kv[a]*wv[0]; acc[a][1] += kv[a]*wv[1];
          acc[a][2] += kv[a]*wv[2]; acc[a][3] += kv[a]*wv[3];
        }
      }
    }
    #pragma unroll
    for (int a = 0; a < 4; a++){
      int tl = tq*4 + a;
      #pragma unroll
      for (int c = 0; c < 4; c++){
        int d = dq*4 + c;
        fpre[((size_t)(b*TT + t0 + tl))*DD + d] = acc[a][c] + f_b[d];
      }
    }
  }

  for (int i = tid; i < 32*DD; i += 256){
    int tl = i >> 7, d = i & 127;
    ypre[((size_t)(b*TT + t0 + tl))*DD + d] =
        a_W[(size_t)d*(NUM_C + DD) + sQ[tl]] * (float)sR[tl] + a_b[d];
  }
}

// ---------------------------------------------------------------------------
// Kernel A2: exact match search (unchanged).
// ---------------------------------------------------------------------------
__global__ __launch_bounds__(512) void kMatch(
    const ull* __restrict__ keyLo, const ull* __restrict__ keyHi, int* __restrict__ prevA)
{
  const int b = blockIdx.x, i = threadIdx.x;
  __shared__ ull slo[TT];
  __shared__ ull shi[TT];
  slo[i] = keyLo[b*TT + i];
  shi[i] = keyHi[b*TT + i];
  __syncthreads();
  const ull mylo = slo[i], myhi = shi[i];
  int found = -1;
  for (int j = i - 1; j >= 0; j--){
    if (slo[j] == mylo && shi[j] == myhi){ found = j; break; }
  }
  prevA[b*TT + i] = found;
}

// ---------------------------------------------------------------------------
// Kernel W: one-time weight products (unchanged).
// ---------------------------------------------------------------------------
__global__ __launch_bounds__(128) void kWW(
    const float* __restrict__ e_W, const float* __restrict__ add_W,
    const float* __restrict__ a_W,
    float* __restrict__ Ge, float* __restrict__ Ga)
{
  const int d = blockIdx.x;    // 0..127
  const int k = threadIdx.x;   // 0..127
  __shared__ float se[128];
  __shared__ float sa[128];
  se[k] = e_W[(size_t)d*DD + k];
  sa[k] = add_W[(size_t)d*DD + k];
  __syncthreads();
  float ge = 0.f, ga = 0.f;
  for (int j = 0; j < DD; j++){
    float af = a_W[(size_t)j*(NUM_C + DD) + NUM_C + k];
    ge += se[j]*af;
    ga += sa[j]*af;
  }
  Ge[(size_t)d*DD + k] = ge;
  Ga[(size_t)d*DD + k] = ga;
}

// ---------------------------------------------------------------------------
// Kernel EA: eapre GEMM (unchanged; eapre now a standalone buffer).
// ---------------------------------------------------------------------------
__global__ __launch_bounds__(256) void kEA(
    const float* __restrict__ ypre, const float* __restrict__ e_W,
    const float* __restrict__ add_W, const float* __restrict__ e_b,
    const float* __restrict__ add_b, float* __restrict__ eapre)
{
  const int jt = blockIdx.x;   // 0..3  (64 output cols each)
  const int rt = blockIdx.y;   // 0..511 (32 rows each)
  const int tid = threadIdx.x;
  __shared__ float sW[64*129];
  __shared__ float sF[32*129];
  for (int i = tid; i < 64*128; i += 256){
    int jj = i >> 7, k = i & 127;
    int j = jt*64 + jj;
    sW[jj*129 + k] = (j < 128) ? e_W[(size_t)j*DD + k] : add_W[(size_t)(j-128)*DD + k];
  }
  for (int i = tid; i < 32*128; i += 256){
    int rr = i >> 7, k = i & 127;
    sF[rr*129 + k] = ypre[(size_t)(rt*32 + rr)*DD + k];
  }
  __syncthreads();
  const int jq = tid & 31, rq = tid >> 5;
  float acc[4][2];
  #pragma unroll
  for (int a = 0; a < 4; a++){ acc[a][0] = 0.f; acc[a][1] = 0.f; }
  for (int k = 0; k < 128; k++){
    float fv[4], wv[2];
    #pragma unroll
    for (int a = 0; a < 4; a++) fv[a] = sF[(rq*4 + a)*129 + k];
    wv[0] = sW[(jq*2 + 0)*129 + k];
    wv[1] = sW[(jq*2 + 1)*129 + k];
    #pragma unroll
    for (int a = 0; a < 4; a++){ acc[a][0] += fv[a]*wv[0]; acc[a][1] += fv[a]*wv[1]; }
  }
  #pragma unroll
  for (int a = 0; a < 4; a++){
    int rowi = rt*32 + rq*4 + a;
    #pragma unroll
    for (int c = 0; c < 2; c++){
      int j = jt*64 + jq*2 + c;
      float bj = (j < 128) ? e_b[j] : add_b[j - 128];
      eapre[(size_t)rowi*256 + j] = acc[a][c] + bj;
    }
  }
}

// ---------------------------------------------------------------------------
// Kernel W4: repack Wih (512x128 row-major) into k-major float4 tiles:
//   Wih4[k4][j][kk] = Wih[j][k4*4+kk]   (float index k4*2048 + j*4 + kk)
// so the fused LSTM role's per-thread GEMM loads are lane-coalesced.
// ---------------------------------------------------------------------------
__global__ __launch_bounds__(256) void kWih4(
    const float* __restrict__ Wih, float* __restrict__ Wih4)
{
  int idx = blockIdx.x*256 + threadIdx.x;     // 0..65535
  int j = idx >> 7, k = idx & 127;
  Wih4[(size_t)(k >> 2)*2048 + j*4 + (k & 3)] = Wih[idx];
}

// ---------------------------------------------------------------------------
// Kernel F (R12): FUSED pipeline — memory recurrence || gates GEMM || LSTM.
// Blocks 0..31  : R11 kMem for batch b; fAll chunk stores use agent-scope
//                 (cross-XCD coherent) atomics; after vmcnt-drain + barrier,
//                 publishes prog[b] = chunks complete (relaxed agent atomic).
// Blocks 32..63 : kLstm for batch b with kGate FOLDED IN: per 8-step chunk,
//                 spin on prog[b], stage the fAll chunk (agent loads, 4 KB),
//                 compute gates_ih = fAll @ Wih^T + bih + bhh in-block into
//                 LDS gbuf (no gpre buffer at all), then run the 8 LSTM steps.
// All 64 blocks co-resident (<< 256 CUs) -> spin-wait is deadlock-free.
// Serial arithmetic identical to R11 kernels; GEMM accumulates k-ascending
// like the old kGate.
// ---------------------------------------------------------------------------
__global__ __launch_bounds__(512, 2) __attribute__((amdgpu_waves_per_eu(2, 2)))
void kFused(
    const float* __restrict__ wAll, const float* __restrict__ fpre,
    const float* __restrict__ eapre, const float* __restrict__ f_W,
    const float* __restrict__ Ge, const float* __restrict__ Ga,
    const float* __restrict__ Mv0, float* __restrict__ fAll,
    const float* __restrict__ Wih4, const float* __restrict__ bih,
    const float* __restrict__ bhh, const int* __restrict__ prevA,
    const float* __restrict__ Whh, float* __restrict__ Hh,
    float* __restrict__ Ch, int* __restrict__ prog)
{
  const int tid = threadIdx.x;
  const int b = blockIdx.x & 31;
  const size_t base = (size_t)b*TT;

  __shared__ __align__(16) union SU {
    struct {
      float bufR[144]; float bufF[144]; float sW9[9*52];
      float sF8[8*128]; float sEA8[8*256]; float fO8[8*128];
    } m;
    struct {
      float xh[2][144]; float gbuf[8*512]; int spv[TT];
      float hRing[8*128]; float cRing[8*128]; float sFc[8*128];
    } l;
  } su;

  if (blockIdx.x < 32){
    // ==================== memory-recurrence role (R11) ====================
    const int dd = tid >> 2, kc = tid & 3, m0 = kc*13;
    const int wslot = (dd >> 5)*36 + (dd & 31);

    float mv[13];
    #pragma unroll
    for (int i = 0; i < 13; i++){
      int m = m0 + i;
      mv[i] = (m < MM) ? Mv0[(size_t)m*DD + dd] : 0.f;
    }
    float wf[32], ge[32], ga[32];
    {
      const float4* p;
      p = reinterpret_cast<const float4*>(&f_W[dd*256 + kc*32]);
      #pragma unroll
      for (int i = 0; i < 8; i++){ float4 v = p[i]; wf[4*i]=v.x; wf[4*i+1]=v.y; wf[4*i+2]=v.z; wf[4*i+3]=v.w; }
      p = reinterpret_cast<const float4*>(&Ge[(size_t)dd*DD + kc*32]);
      #pragma unroll
      for (int i = 0; i < 8; i++){ float4 v = p[i]; ge[4*i]=v.x; ge[4*i+1]=v.y; ge[4*i+2]=v.z; ge[4*i+3]=v.w; }
      p = reinterpret_cast<const float4*>(&Ga[(size_t)dd*DD + kc*32]);
      #pragma unroll
      for (int i = 0; i < 8; i++){ float4 v = p[i]; ga[4*i]=v.x; ga[4*i+1]=v.y; ga[4*i+2]=v.z; ga[4*i+3]=v.w; }
    }

    const int rr0 = tid / 50, mm0 = tid - rr0*50;   // valid when tid < 450
    if (tid < 18){ int rr = tid >> 1; su.m.sW9[rr*52 + 50 + (tid & 1)] = 0.f; }

    float4 pF = {0.f,0.f,0.f,0.f}, pEA = {0.f,0.f,0.f,0.f};
    float pW = 0.f;
    if (tid < 256) pF = reinterpret_cast<const float4*>(&fpre[base*DD])[tid];
    pEA = reinterpret_cast<const float4*>(&eapre[base*256])[tid];
    if (tid < 450) pW = wAll[(base + rr0)*MM + mm0];

    float wreg[13];

    for (int ch = 0; ch < TT/8; ch++){
      const int t0 = ch*8;
      if (ch){
        if (tid < 256){
          float4 v = reinterpret_cast<const float4*>(su.m.fO8)[tid];
          float* dst = &fAll[(base + t0 - 8)*DD + tid*4];
          __hip_atomic_store(dst+0, v.x, __ATOMIC_RELAXED, __HIP_MEMORY_SCOPE_AGENT);
          __hip_atomic_store(dst+1, v.y, __ATOMIC_RELAXED, __HIP_MEMORY_SCOPE_AGENT);
          __hip_atomic_store(dst+2, v.z, __ATOMIC_RELAXED, __HIP_MEMORY_SCOPE_AGENT);
          __hip_atomic_store(dst+3, v.w, __ATOMIC_RELAXED, __HIP_MEMORY_SCOPE_AGENT);
        }
      }
      if (tid < 256) reinterpret_cast<float4*>(su.m.sF8)[tid] = pF;
      reinterpret_cast<float4*>(su.m.sEA8)[tid] = pEA;
      if (tid < 450) su.m.sW9[rr0*52 + mm0] = pW;
      if (ch && tid < 256) waitVM_();     // chunk stores complete before flag
      if (t0 + 8 < TT){
        if (tid < 256) pF = reinterpret_cast<const float4*>(&fpre[(base + t0 + 8)*DD])[tid];
        pEA = reinterpret_cast<const float4*>(&eapre[(base + t0 + 8)*256])[tid];
        if (tid < 450) pW = (t0 + 8 + rr0 < TT) ? wAll[(base + t0 + 8 + rr0)*MM + mm0] : 0.f;
      }
      barL_();   // R: chunk published (and all chunk stores drained)
      if (ch && tid == 0)
        __hip_atomic_store(&prog[b], ch, __ATOMIC_RELAXED, __HIP_MEMORY_SCOPE_AGENT);

      if (ch == 0){
        #pragma unroll
        for (int i = 0; i < 13; i++) wreg[i] = su.m.sW9[m0 + i];
        float r = 0.f;
        #pragma unroll
        for (int i = 0; i < 13; i++) r += wreg[i]*mv[i];
        r = quadSum_(r);
        if (kc == 0) su.m.bufR[wslot] = r;
        barL_();
      }

      #pragma unroll
      for (int tc = 0; tc < 8; tc++){
        float wn[13];
        #pragma unroll
        for (int i = 0; i < 13; i++) wn[i] = su.m.sW9[(tc+1)*52 + m0 + i];

        // ---- stage F: f = tanh(read @ f_Wr.T + fpre) ----
        {
          const float4* x4 = reinterpret_cast<const float4*>(&su.m.bufR[kc*36]);
          float a0=0.f,a1=0.f,a2=0.f,a3=0.f;
          #pragma unroll
          for (int i = 0; i < 8; i++){
            float4 xv = x4[i];
            a0 += xv.x*wf[4*i]; a1 += xv.y*wf[4*i+1]; a2 += xv.z*wf[4*i+2]; a3 += xv.w*wf[4*i+3];
          }
          float s = quadSum_((a0+a1)+(a2+a3));
          float fval = fast_tanh_(s + su.m.sF8[tc*128 + dd]);
          if (kc == 0){
            su.m.bufF[wslot] = fval;
            su.m.fO8[tc*128 + dd] = fval;
          }
        }
        barL_();   // B

        // ---- stage EA: e,a from f; mv update; read_{t+1} = wn . mv_new ----
        {
          const float4* x4 = reinterpret_cast<const float4*>(&su.m.bufF[kc*36]);
          float e0=0.f,e1=0.f,g0=0.f,g1=0.f;
          #pragma unroll
          for (int i = 0; i < 8; i++){
            float4 xv = x4[i];
            e0 += xv.x*ge[4*i];   e1 += xv.y*ge[4*i+1];
            e0 += xv.z*ge[4*i+2]; e1 += xv.w*ge[4*i+3];
            g0 += xv.x*ga[4*i];   g1 += xv.y*ga[4*i+1];
            g0 += xv.z*ga[4*i+2]; g1 += xv.w*ga[4*i+3];
          }
          float ep = quadSum_(e0 + e1);
          float ap = quadSum_(g0 + g1);
          float e_d = fast_sig_(ep + su.m.sEA8[tc*256 + dd]);
          float a_d = fast_tanh_(ap + su.m.sEA8[tc*256 + 128 + dd]);
          float rp0 = 0.f, rp1 = 0.f;
          #pragma unroll
          for (int i = 0; i < 13; i++){
            float t = __builtin_fmaf(-e_d, mv[i], a_d);
            mv[i] = __builtin_fmaf(wreg[i], t, mv[i]);
            if (i & 1) rp1 = __builtin_fmaf(wn[i], mv[i], rp1);
            else       rp0 = __builtin_fmaf(wn[i], mv[i], rp0);
          }
          float rd = quadSum_(rp0 + rp1);
          if (kc == 0) su.m.bufR[wslot] = rd;
        }
        #pragma unroll
        for (int i = 0; i < 13; i++) wreg[i] = wn[i];
        barL_();   // C
      }
    }

    // tail: store last chunk + final flag
    if (tid < 256){
      float4 v = reinterpret_cast<const float4*>(su.m.fO8)[tid];
      float* dst = &fAll[(base + TT - 8)*DD + tid*4];
      __hip_atomic_store(dst+0, v.x, __ATOMIC_RELAXED, __HIP_MEMORY_SCOPE_AGENT);
      __hip_atomic_store(dst+1, v.y, __ATOMIC_RELAXED, __HIP_MEMORY_SCOPE_AGENT);
      __hip_atomic_store(dst+2, v.z, __ATOMIC_RELAXED, __HIP_MEMORY_SCOPE_AGENT);
      __hip_atomic_store(dst+3, v.w, __ATOMIC_RELAXED, __HIP_MEMORY_SCOPE_AGENT);
      waitVM_();
    }
    __syncthreads();
    if (tid == 0)
      __hip_atomic_store(&prog[b], TT/8, __ATOMIC_RELAXED, __HIP_MEMORY_SCOPE_AGENT);

  } else {
    // ==================== LSTM role (kGate folded in) ====================
    const int jo = tid >> 2, kc = tid & 3;
    const int wslot = (jo >> 5)*36 + (jo & 31);

    float whh[4][32];
    #pragma unroll
    for (int g = 0; g < 4; g++){
      const float4* W4 = reinterpret_cast<const float4*>(&Whh[(size_t)(g*128 + jo)*128 + kc*32]);
      #pragma unroll
      for (int i = 0; i < 8; i++){
        float4 v = W4[i];
        whh[g][4*i] = v.x; whh[g][4*i+1] = v.y; whh[g][4*i+2] = v.z; whh[g][4*i+3] = v.w;
      }
    }
    const float biasj = bih[tid] + bhh[tid];   // thread owns gate-column j = tid

    su.l.spv[tid] = prevA[base + tid];
    if (tid < DD) su.l.xh[0][(tid >> 5)*36 + (tid & 31)] = 0.f;

    float cin_cur = 0.f;

    for (int ch = 0; ch < TT/8; ch++){
      const int t0 = ch*8;
      if (ch) __syncthreads();   // FULL: drains prev chunk's Hh/Ch stores

      // wait for the producer's chunk ch, then stage it (agent loads bypass
      // this XCD's possibly-stale L2 — §G16)
      if (tid == 0){
        while (__hip_atomic_load(&prog[b], __ATOMIC_ACQUIRE, __HIP_MEMORY_SCOPE_AGENT) < ch + 1)
          __builtin_amdgcn_s_sleep(2);
      }
      __syncthreads();
      if (tid < 256){
        const float* src = &fAll[(base + t0)*DD + tid*4];
        float x0 = __hip_atomic_load(src+0, __ATOMIC_RELAXED, __HIP_MEMORY_SCOPE_AGENT);
        float x1 = __hip_atomic_load(src+1, __ATOMIC_RELAXED, __HIP_MEMORY_SCOPE_AGENT);
        float x2 = __hip_atomic_load(src+2, __ATOMIC_RELAXED, __HIP_MEMORY_SCOPE_AGENT);
        float x3 = __hip_atomic_load(src+3, __ATOMIC_RELAXED, __HIP_MEMORY_SCOPE_AGENT);
        su.l.sFc[tid*4+0] = x0; su.l.sFc[tid*4+1] = x1;
        su.l.sFc[tid*4+2] = x2; su.l.sFc[tid*4+3] = x3;
      }
      barL_();

      // gates GEMM: gbuf[tc][j] = dot(fAll[t0+tc][:], Wih[j][:]) + bih[j]+bhh[j]
      {
        float acc[8];
        #pragma unroll
        for (int u = 0; u < 8; u++) acc[u] = 0.f;
        for (int k4 = 0; k4 < 32; k4++){
          float4 wv = reinterpret_cast<const float4*>(Wih4)[k4*512 + tid];
          #pragma unroll
          for (int u = 0; u < 8; u++){
            float4 fv = *reinterpret_cast<const float4*>(&su.l.sFc[u*128 + k4*4]);
            acc[u] += fv.x*wv.x; acc[u] += fv.y*wv.y;
            acc[u] += fv.z*wv.z; acc[u] += fv.w*wv.w;
          }
        }
        #pragma unroll
        for (int u = 0; u < 8; u++) su.l.gbuf[u*512 + tid] = acc[u] + biasj;
      }
      barL_();   // gbuf published (+ xh ready for tc=0)

      #pragma unroll
      for (int tc = 0; tc < 8; tc++){
        const int t = t0 + tc, p = t & 1;
        if (tc) barL_();                 // xh[p] + ring ready

        int pv2 = -1; float preH = 0.f, preC = 0.f;
        if (t + 1 < TT){
          pv2 = su.l.spv[t + 1];
          if (pv2 >= 0 && pv2 < t){
            if (pv2 >= t0){              // in-chunk: LDS ring
              preH = su.l.hRing[(pv2 & 7)*128 + jo];
              preC = su.l.cRing[(pv2 & 7)*128 + jo];
            } else {                     // older chunk: global (same block wrote it)
              preH = Hh[(base + pv2)*DD + jo];
              preC = Ch[(base + pv2)*DD + jo];
            }
          }
        }

        float gp0 = su.l.gbuf[tc*512 + jo];
        float gp1 = su.l.gbuf[tc*512 + 128 + jo];
        float gp2 = su.l.gbuf[tc*512 + 256 + jo];
        float gp3 = su.l.gbuf[tc*512 + 384 + jo];

        float a0=0.f,a1=0.f,a2=0.f,a3=0.f;
        {
          const float4* x4 = reinterpret_cast<const float4*>(&su.l.xh[p][kc*36]);
          #pragma unroll
          for (int i = 0; i < 8; i++){
            float4 xv = x4[i];
            a0 += xv.x*whh[0][4*i]; a0 += xv.y*whh[0][4*i+1]; a0 += xv.z*whh[0][4*i+2]; a0 += xv.w*whh[0][4*i+3];
            a1 += xv.x*whh[1][4*i]; a1 += xv.y*whh[1][4*i+1]; a1 += xv.z*whh[1][4*i+2]; a1 += xv.w*whh[1][4*i+3];
            a2 += xv.x*whh[2][4*i]; a2 += xv.y*whh[2][4*i+1]; a2 += xv.z*whh[2][4*i+2]; a2 += xv.w*whh[2][4*i+3];
            a3 += xv.x*whh[3][4*i]; a3 += xv.y*whh[3][4*i+1]; a3 += xv.z*whh[3][4*i+2]; a3 += xv.w*whh[3][4*i+3];
          }
        }
        a0 = quadSum_(a0); a1 = quadSum_(a1); a2 = quadSum_(a2); a3 = quadSum_(a3);

        const float ig = gp0 + a0, fg = gp1 + a1, gg = gp2 + a2, og = gp3 + a3;
        const float cn = fast_sig_(fg)*cin_cur + fast_sig_(ig)*fast_tanh_(gg);
        const float hn = fast_sig_(og)*fast_tanh_(cn);

        if (kc == 0){
          Hh[(base + t)*DD + jo] = hn;
          Ch[(base + t)*DD + jo] = cn;
          su.l.hRing[(t & 7)*128 + jo] = hn;
          su.l.cRing[(t & 7)*128 + jo] = cn;
        }

        float hin_n, cin_n;
        if (pv2 < 0 || pv2 >= t){ hin_n = hn; cin_n = cn; }       // carry
        else                     { hin_n = preH; cin_n = preC; }   // skip
        if (kc == 0) su.l.xh[1 - p][wslot] = hin_n;
        cin_cur = cin_n;
      }
    }
  }
}

// ---------------------------------------------------------------------------
// Kernel E: output head (unchanged).
// ---------------------------------------------------------------------------
__global__ __launch_bounds__(256) void kOut(
    const float* __restrict__ Hh, const float* __restrict__ p_W,
    const float* __restrict__ p_b, float* __restrict__ out)
{
  const int row = blockIdx.x*16 + (threadIdx.x >> 4);
  const int l = threadIdx.x & 15;
  const float4* h4 = reinterpret_cast<const float4*>(&Hh[(size_t)row*DD + l*8]);
  const float4* w4 = reinterpret_cast<const float4*>(&p_W[l*8]);
  float4 ha = h4[0], hb = h4[1], wa = w4[0], wb = w4[1];
  float s = ha.x*wa.x + ha.y*wa.y + ha.z*wa.z + ha.w*wa.w
          + hb.x*wb.x + hb.y*wb.y + hb.z*wb.z + hb.w*wb.w;
  s += __shfl_xor(s, 1); s += __shfl_xor(s, 2);
  s += __shfl_xor(s, 4); s += __shfl_xor(s, 8);
  if (l == 0) out[row] = sigmoidf_(s + p_b[0]);
}

// ---------------------------------------------------------------------------
// Launch.
// ---------------------------------------------------------------------------
extern "C" void kernel_launch(void* const* d_in, const int* in_sizes, int n_in,
                              void* d_out, int out_size, void* d_ws, size_t ws_size,
                              hipStream_t stream) {
  const int*   q     = (const int*)  d_in[0];
  const int*   r     = (const int*)  d_in[1];
  const float* k_emb = (const float*)d_in[2];
  const float* Mk    = (const float*)d_in[3];
  const float* Mv0   = (const float*)d_in[4];
  const float* f_W   = (const float*)d_in[5];
  const float* f_b   = (const float*)d_in[6];
  const float* a_W   = (const float*)d_in[7];
  const float* a_b   = (const float*)d_in[8];
  const float* e_W   = (const float*)d_in[9];
  const float* e_b   = (const float*)d_in[10];
  const float* add_W = (const float*)d_in[11];
  const float* add_b = (const float*)d_in[12];
  const float* Wih   = (const float*)d_in[13];
  const float* Whh   = (const float*)d_in[14];
  const float* bih   = (const float*)d_in[15];
  const float* bhh   = (const float*)d_in[16];
  const float* p_W   = (const float*)d_in[17];
  const float* p_b   = (const float*)d_in[18];
  float* out = (float*)d_out;

  char* ws = (char*)d_ws;
  size_t off = 0;
  auto alloc = [&](size_t bytes) -> char* {
    char* p = ws + off;
    off += (bytes + 255) & ~(size_t)255;
    return p;
  };
  float* wAll  = (float*)alloc((size_t)BB*TT*MM*4);
  float* fpre  = (float*)alloc((size_t)BB*TT*DD*4);
  float* ypre  = (float*)alloc((size_t)BB*TT*DD*4);
  float* fAll  = (float*)alloc((size_t)BB*TT*DD*4);
  float* eapre = (float*)alloc((size_t)BB*TT*256*4);   // standalone (gpre gone)
  float* Hh    = (float*)alloc((size_t)BB*TT*DD*4);
  float* Ch    = (float*)alloc((size_t)BB*TT*DD*4);
  ull*   keyLo = (ull*)  alloc((size_t)BB*TT*8);
  ull*   keyHi = (ull*)  alloc((size_t)BB*TT*8);
  int*   prevA = (int*)  alloc((size_t)BB*TT*4);
  float* Ge    = (float*)alloc((size_t)DD*DD*4);
  float* Ga    = (float*)alloc((size_t)DD*DD*4);
  float* Wih4  = (float*)alloc((size_t)512*DD*4);
  int*   prog  = (int*)  alloc(256);
  (void)ws_size; (void)in_sizes; (void)n_in; (void)out_size;

  hipMemsetAsync(prog, 0, 32*sizeof(int), stream);   // reset pipeline flags
  kPre  <<<dim3(16, 32), 256, 0, stream>>>(q, r, k_emb, Mk, f_W, f_b, a_W, a_b,
                                           wAll, keyLo, keyHi, fpre, ypre);
  kWW   <<<128, 128, 0, stream>>>(e_W, add_W, a_W, Ge, Ga);
  kEA   <<<dim3(4, 512), 256, 0, stream>>>(ypre, e_W, add_W, e_b, add_b, eapre);
  kWih4 <<<256, 256, 0, stream>>>(Wih, Wih4);
  kMatch<<<32, 512, 0, stream>>>(keyLo, keyHi, prevA);
  kFused<<<64, 512, 0, stream>>>(wAll, fpre, eapre, f_W, Ge, Ga, Mv0, fAll,
                                 Wih4, bih, bhh, prevA, Whh, Hh, Ch, prog);
  kOut  <<<(BB*TT)/16, 256, 0, stream>>>(Hh, p_W, p_b, out);
}